// Round 2
// baseline (1749.456 us; speedup 1.0000x reference)
//
#include <hip/hip_runtime.h>

#define N_NODES 50000
#define N_EDGES 600000
#define DIM 128
#define NCLS 10
#define EPSF 1e-15f
#define MAXNORM 0.99999f  // 1 - 1e-5

__device__ inline float waveSum(float v) {
#pragma unroll
  for (int o = 1; o < 64; o <<= 1) v += __shfl_xor(v, o, 64);
  return v;
}

// Fused logmap0 -> linear (W row-major [Dout=128][Din=128], h = W*t + b) -> expmap0
// One block (128 threads) per node. relu_in applies relu to the input row first.
__global__ __launch_bounds__(128) void transform_kernel(
    const float* __restrict__ x, const float* __restrict__ W,
    const float* __restrict__ b, float* __restrict__ y, int relu_in)
{
  const int node = blockIdx.x;
  const int d = threadIdx.x;  // 0..127
  __shared__ float t[DIM];
  __shared__ float red[2];

  float v = x[(size_t)node * DIM + d];
  if (relu_in) v = fmaxf(v, 0.0f);

  // ||x|| across the 128-thread block (2 waves)
  float s = waveSum(v * v);
  if ((d & 63) == 0) red[d >> 6] = s;
  __syncthreads();
  float n = sqrtf(red[0] + red[1]);
  float nc = fmaxf(n, EPSF);
  float nm = fminf(nc, MAXNORM);
  // artanh(nm)/nc
  float scale = 0.5f * logf((1.0f + nm) / (1.0f - nm)) / nc;
  t[d] = v * scale;
  __syncthreads();   // t visible; red reads done

  // h[d] = b[d] + sum_k t[k] * W[d][k]
  float acc = b[d];
  const float4* Wr = (const float4*)(W + (size_t)d * DIM);
  const float4* tv = (const float4*)t;
#pragma unroll 8
  for (int k = 0; k < DIM / 4; ++k) {
    float4 w4 = Wr[k];
    float4 t4 = tv[k];  // broadcast across lanes
    acc += w4.x * t4.x + w4.y * t4.y + w4.z * t4.z + w4.w * t4.w;
  }

  // expmap0
  float s2 = waveSum(acc * acc);
  if ((d & 63) == 0) red[d >> 6] = s2;   // safe: all red reads happened pre-barrier
  __syncthreads();
  float n2 = sqrtf(red[0] + red[1]);
  float n2c = fmaxf(n2, EPSF);
  float sc2 = tanhf(n2c) / n2c;
  y[(size_t)node * DIM + d] = acc * sc2;
}

// segment_sum: one wave per edge, 64 lanes x float2 = 512B row; atomicAdd into dst row.
__global__ __launch_bounds__(256) void scatter_kernel(
    const float* __restrict__ y, const int* __restrict__ src,
    const int* __restrict__ dst, float* __restrict__ out)
{
  const int e = blockIdx.x * 4 + (threadIdx.x >> 6);
  if (e >= N_EDGES) return;
  const int lane = threadIdx.x & 63;
  const int s = src[e];   // wave-uniform
  const int dd = dst[e];
  const float2 v = ((const float2*)(y + (size_t)s * DIM))[lane];
  float* o = out + (size_t)dd * DIM + lane * 2;
  atomicAdd(o, v.x);
  atomicAdd(o + 1, v.y);
}

// Fused relu -> logmap0 -> t @ Wc^T + bc.  One block (128 threads) per node.
__global__ __launch_bounds__(128) void classify_kernel(
    const float* __restrict__ h, const float* __restrict__ Wc,
    const float* __restrict__ bc, float* __restrict__ out)
{
  const int node = blockIdx.x;
  const int d = threadIdx.x;
  __shared__ float t[DIM];
  __shared__ float red[2];

  float v = fmaxf(h[(size_t)node * DIM + d], 0.0f);
  float s = waveSum(v * v);
  if ((d & 63) == 0) red[d >> 6] = s;
  __syncthreads();
  float n = sqrtf(red[0] + red[1]);
  float nc = fmaxf(n, EPSF);
  float nm = fminf(nc, MAXNORM);
  float scale = 0.5f * logf((1.0f + nm) / (1.0f - nm)) / nc;
  t[d] = v * scale;
  __syncthreads();

  const int lane = d & 63;
  const int wid = d >> 6;
  const float2 tl = ((const float2*)t)[lane];
  for (int c = wid; c < NCLS; c += 2) {
    const float2 w2 = ((const float2*)(Wc + (size_t)c * DIM))[lane];
    float p = tl.x * w2.x + tl.y * w2.y;
    p = waveSum(p);
    if (lane == 0) out[(size_t)node * NCLS + c] = p + bc[c];
  }
}

extern "C" void kernel_launch(void* const* d_in, const int* in_sizes, int n_in,
                              void* d_out, int out_size, void* d_ws, size_t ws_size,
                              hipStream_t stream)
{
  const int* edge = (const int*)d_in[0];
  const int* src = edge;            // edge_index[0]
  const int* dst = edge + N_EDGES;  // edge_index[1]
  const float* x  = (const float*)d_in[1];
  const float* W1 = (const float*)d_in[2];
  const float* b1 = (const float*)d_in[3];
  const float* W2 = (const float*)d_in[4];
  const float* b2 = (const float*)d_in[5];
  const float* Wc = (const float*)d_in[6];
  const float* bc = (const float*)d_in[7];
  float* out = (float*)d_out;

  float* bufA = (float*)d_ws;                       // y (transform output)
  float* bufB = bufA + (size_t)N_NODES * DIM;       // h (segment_sum accumulator)
  const size_t rowBytes = (size_t)N_NODES * DIM * sizeof(float);

  // Layer 1
  transform_kernel<<<N_NODES, 128, 0, stream>>>(x, W1, b1, bufA, 0);
  hipMemsetAsync(bufB, 0, rowBytes, stream);
  scatter_kernel<<<(N_EDGES + 3) / 4, 256, 0, stream>>>(bufA, src, dst, bufB);

  // Layer 2 (relu fused into input read)
  transform_kernel<<<N_NODES, 128, 0, stream>>>(bufB, W2, b2, bufA, 1);
  hipMemsetAsync(bufB, 0, rowBytes, stream);
  scatter_kernel<<<(N_EDGES + 3) / 4, 256, 0, stream>>>(bufA, src, dst, bufB);

  // Classifier (relu fused)
  classify_kernel<<<N_NODES, 128, 0, stream>>>(bufB, Wc, bc, out);
}

// Round 3
// 381.098 us; speedup vs baseline: 4.5906x; 4.5906x over previous
//
#include <hip/hip_runtime.h>

#define N_NODES 50000
#define N_EDGES 600000
#define DIM 128
#define NCLS 10
#define EPSF 1e-15f
#define MAXNORM 0.99999f  // 1 - 1e-5

__device__ inline float waveSum(float v) {
#pragma unroll
  for (int o = 1; o < 64; o <<= 1) v += __shfl_xor(v, o, 64);
  return v;
}

// ---------------- CSR build ----------------

__global__ __launch_bounds__(256) void hist_kernel(
    const int* __restrict__ dst, int* __restrict__ off)
{
  int e = blockIdx.x * 256 + threadIdx.x;
  if (e < N_EDGES) atomicAdd(&off[dst[e] + 1], 1);
}

// Block-wise inclusive scan of off[0..N_NODES] (50001 ints), 1024/block.
__global__ __launch_bounds__(1024) void scan1_kernel(
    int* __restrict__ off, int* __restrict__ bsum)
{
  const int gid = blockIdx.x * 1024 + threadIdx.x;
  const int lane = threadIdx.x & 63, wid = threadIdx.x >> 6;
  __shared__ int ws[16];
  int v = (gid <= N_NODES) ? off[gid] : 0;
#pragma unroll
  for (int o = 1; o < 64; o <<= 1) {
    int u = __shfl_up(v, o, 64);
    if (lane >= o) v += u;
  }
  if (lane == 63) ws[wid] = v;
  __syncthreads();
  if (wid == 0) {
    int z = (lane < 16) ? ws[lane] : 0;
#pragma unroll
    for (int o = 1; o < 16; o <<= 1) {
      int u = __shfl_up(z, o, 64);
      if (lane >= o) z += u;
    }
    if (lane < 16) ws[lane] = z;
  }
  __syncthreads();
  if (wid > 0) v += ws[wid - 1];
  if (gid <= N_NODES) off[gid] = v;
  if (threadIdx.x == 1023) bsum[blockIdx.x] = v;
}

// Exclusive scan of the 49 block sums (single wave).
__global__ __launch_bounds__(64) void scan2_kernel(int* __restrict__ bsum, int nchunk)
{
  const int lane = threadIdx.x;
  int v = (lane < nchunk) ? bsum[lane] : 0;
#pragma unroll
  for (int o = 1; o < 64; o <<= 1) {
    int u = __shfl_up(v, o, 64);
    if (lane >= o) v += u;
  }
  int ex = __shfl_up(v, 1, 64);
  if (lane == 0) ex = 0;
  if (lane < nchunk) bsum[lane] = ex;
}

// Add carries; also initialize pos[] = final offsets.
__global__ __launch_bounds__(256) void scan3_kernel(
    int* __restrict__ off, const int* __restrict__ bsum, int* __restrict__ pos)
{
  int gid = blockIdx.x * 256 + threadIdx.x;
  if (gid <= N_NODES) {
    int v = off[gid] + bsum[gid >> 10];
    off[gid] = v;
    if (gid < N_NODES) pos[gid] = v;
  }
}

__global__ __launch_bounds__(256) void fill_kernel(
    const int* __restrict__ src, const int* __restrict__ dst,
    int* __restrict__ pos, int* __restrict__ csr_src)
{
  int e = blockIdx.x * 256 + threadIdx.x;
  if (e < N_EDGES) {
    int slot = atomicAdd(&pos[dst[e]], 1);
    csr_src[slot] = src[e];
  }
}

// ---------------- gather (segment_sum via CSR) ----------------
// One wave per destination node; 64 lanes x float2 = 512B row; register accumulate.
__global__ __launch_bounds__(256) void gather_kernel(
    const float* __restrict__ y, const int* __restrict__ off,
    const int* __restrict__ csr_src, float* __restrict__ out)
{
  const int node = blockIdx.x * 4 + (threadIdx.x >> 6);
  if (node >= N_NODES) return;
  const int lane = threadIdx.x & 63;
  const int beg = off[node], end = off[node + 1];
  float2 a0 = {0.f, 0.f}, a1 = {0.f, 0.f};
  int j = beg;
  for (; j + 1 < end; j += 2) {
    int s0 = csr_src[j], s1 = csr_src[j + 1];
    float2 v0 = ((const float2*)(y + (size_t)s0 * DIM))[lane];
    float2 v1 = ((const float2*)(y + (size_t)s1 * DIM))[lane];
    a0.x += v0.x; a0.y += v0.y;
    a1.x += v1.x; a1.y += v1.y;
  }
  if (j < end) {
    int s0 = csr_src[j];
    float2 v0 = ((const float2*)(y + (size_t)s0 * DIM))[lane];
    a0.x += v0.x; a0.y += v0.y;
  }
  float2 r;
  r.x = a0.x + a1.x;
  r.y = a0.y + a1.y;
  ((float2*)(out + (size_t)node * DIM))[lane] = r;
}

// ---------------- fused logmap0 -> W*t+b -> expmap0 ----------------
// Grid-strided; each thread caches its W row (128 floats) in VGPRs once per block.
__global__ __launch_bounds__(128) void transform_kernel(
    const float* __restrict__ x, const float* __restrict__ W,
    const float* __restrict__ b, float* __restrict__ y, int relu_in)
{
  const int d = threadIdx.x;  // 0..127 output dim
  __shared__ float t[DIM];
  __shared__ float red[4];

  float4 wv[32];
  const float4* Wr4 = (const float4*)(W + (size_t)d * DIM);
#pragma unroll
  for (int k = 0; k < 32; ++k) wv[k] = Wr4[k];
  const float bd = b[d];

  for (int node = blockIdx.x; node < N_NODES; node += gridDim.x) {
    float v = x[(size_t)node * DIM + d];
    if (relu_in) v = fmaxf(v, 0.0f);
    float s = waveSum(v * v);
    __syncthreads();  // #1: previous iteration's shared reads complete
    if ((d & 63) == 0) red[d >> 6] = s;
    __syncthreads();  // #2
    float n = sqrtf(red[0] + red[1]);
    float nc = fmaxf(n, EPSF);
    float nm = fminf(nc, MAXNORM);
    float scale = 0.5f * logf((1.0f + nm) / (1.0f - nm)) / nc;
    t[d] = v * scale;
    __syncthreads();  // #3: t visible

    float4 a;
    a.x = bd; a.y = 0.f; a.z = 0.f; a.w = 0.f;
    const float4* tv = (const float4*)t;
#pragma unroll
    for (int k = 0; k < 32; ++k) {
      float4 t4 = tv[k];  // broadcast
      a.x += wv[k].x * t4.x;
      a.y += wv[k].y * t4.y;
      a.z += wv[k].z * t4.z;
      a.w += wv[k].w * t4.w;
    }
    float acc = (a.x + a.y) + (a.z + a.w);

    float s2 = waveSum(acc * acc);
    if ((d & 63) == 0) red[2 + (d >> 6)] = s2;  // separate slots, no conflict
    __syncthreads();  // #4
    float n2 = sqrtf(red[2] + red[3]);
    float n2c = fmaxf(n2, EPSF);
    float sc2 = tanhf(n2c) / n2c;
    y[(size_t)node * DIM + d] = acc * sc2;
  }
}

// ---------------- fused relu -> logmap0 -> t @ Wc^T + bc ----------------
__global__ __launch_bounds__(128) void classify_kernel(
    const float* __restrict__ h, const float* __restrict__ Wc,
    const float* __restrict__ bc, float* __restrict__ out)
{
  const int node = blockIdx.x;
  const int d = threadIdx.x;
  __shared__ float t[DIM];
  __shared__ float red[2];

  float v = fmaxf(h[(size_t)node * DIM + d], 0.0f);
  float s = waveSum(v * v);
  if ((d & 63) == 0) red[d >> 6] = s;
  __syncthreads();
  float n = sqrtf(red[0] + red[1]);
  float nc = fmaxf(n, EPSF);
  float nm = fminf(nc, MAXNORM);
  float scale = 0.5f * logf((1.0f + nm) / (1.0f - nm)) / nc;
  t[d] = v * scale;
  __syncthreads();

  const int lane = d & 63;
  const int wid = d >> 6;
  const float2 tl = ((const float2*)t)[lane];
  for (int c = wid; c < NCLS; c += 2) {
    const float2 w2 = ((const float2*)(Wc + (size_t)c * DIM))[lane];
    float p = tl.x * w2.x + tl.y * w2.y;
    p = waveSum(p);
    if (lane == 0) out[(size_t)node * NCLS + c] = p + bc[c];
  }
}

extern "C" void kernel_launch(void* const* d_in, const int* in_sizes, int n_in,
                              void* d_out, int out_size, void* d_ws, size_t ws_size,
                              hipStream_t stream)
{
  const int* edge = (const int*)d_in[0];
  const int* src = edge;            // edge_index[0]
  const int* dst = edge + N_EDGES;  // edge_index[1]
  const float* x  = (const float*)d_in[1];
  const float* W1 = (const float*)d_in[2];
  const float* b1 = (const float*)d_in[3];
  const float* W2 = (const float*)d_in[4];
  const float* b2 = (const float*)d_in[5];
  const float* Wc = (const float*)d_in[6];
  const float* bc = (const float*)d_in[7];
  float* out = (float*)d_out;

  float* bufA = (float*)d_ws;                    // transform output y
  float* bufB = bufA + (size_t)N_NODES * DIM;    // gather output h
  int* off  = (int*)(bufB + (size_t)N_NODES * DIM);  // 50001
  int* bsum = off + N_NODES + 4;                     // 64
  int* pos  = bsum + 64;                             // 50000
  int* csr  = pos + N_NODES;                         // 600000

  const int NCHUNK = (N_NODES + 1 + 1023) / 1024;  // 49

  // --- CSR build (dst identical for both layers; build once) ---
  hipMemsetAsync(off, 0, (N_NODES + 1) * sizeof(int), stream);
  hist_kernel<<<(N_EDGES + 255) / 256, 256, 0, stream>>>(dst, off);
  scan1_kernel<<<NCHUNK, 1024, 0, stream>>>(off, bsum);
  scan2_kernel<<<1, 64, 0, stream>>>(bsum, NCHUNK);
  scan3_kernel<<<(N_NODES + 256) / 256, 256, 0, stream>>>(off, bsum, pos);
  fill_kernel<<<(N_EDGES + 255) / 256, 256, 0, stream>>>(src, dst, pos, csr);

  // --- Layer 1 ---
  transform_kernel<<<1536, 128, 0, stream>>>(x, W1, b1, bufA, 0);
  gather_kernel<<<(N_NODES + 3) / 4, 256, 0, stream>>>(bufA, off, csr, bufB);

  // --- Layer 2 (relu fused into input read) ---
  transform_kernel<<<1536, 128, 0, stream>>>(bufB, W2, b2, bufA, 1);
  gather_kernel<<<(N_NODES + 3) / 4, 256, 0, stream>>>(bufA, off, csr, bufB);

  // --- Classifier (relu fused) ---
  classify_kernel<<<N_NODES, 128, 0, stream>>>(bufB, Wc, bc, out);
}

// Round 4
// 296.715 us; speedup vs baseline: 5.8961x; 1.2844x over previous
//
#include <hip/hip_runtime.h>

#define N_NODES 50000
#define N_EDGES 600000
#define DIM 128
#define NCLS 10
#define EPSF 1e-15f
#define MAXNORM 0.99999f  // 1 - 1e-5

typedef __attribute__((ext_vector_type(8))) short bf16x8;
typedef __attribute__((ext_vector_type(4))) float f32x4;

__device__ inline float waveSum(float v) {
#pragma unroll
  for (int o = 1; o < 64; o <<= 1) v += __shfl_xor(v, o, 64);
  return v;
}

__device__ inline unsigned short f2bf(float f) {
  union { float f; unsigned u; } c; c.f = f;
  return (unsigned short)((c.u + 0x7FFFu + ((c.u >> 16) & 1u)) >> 16);
}

// ---------------- CSR build ----------------

__global__ __launch_bounds__(256) void hist_kernel(
    const int* __restrict__ dst, int* __restrict__ off)
{
  int e = blockIdx.x * 256 + threadIdx.x;
  if (e < N_EDGES) atomicAdd(&off[dst[e] + 1], 1);
}

__global__ __launch_bounds__(1024) void scan1_kernel(
    int* __restrict__ off, int* __restrict__ bsum)
{
  const int gid = blockIdx.x * 1024 + threadIdx.x;
  const int lane = threadIdx.x & 63, wid = threadIdx.x >> 6;
  __shared__ int ws[16];
  int v = (gid <= N_NODES) ? off[gid] : 0;
#pragma unroll
  for (int o = 1; o < 64; o <<= 1) {
    int u = __shfl_up(v, o, 64);
    if (lane >= o) v += u;
  }
  if (lane == 63) ws[wid] = v;
  __syncthreads();
  if (wid == 0) {
    int z = (lane < 16) ? ws[lane] : 0;
#pragma unroll
    for (int o = 1; o < 16; o <<= 1) {
      int u = __shfl_up(z, o, 64);
      if (lane >= o) z += u;
    }
    if (lane < 16) ws[lane] = z;
  }
  __syncthreads();
  if (wid > 0) v += ws[wid - 1];
  if (gid <= N_NODES) off[gid] = v;
  if (threadIdx.x == 1023) bsum[blockIdx.x] = v;
}

__global__ __launch_bounds__(64) void scan2_kernel(int* __restrict__ bsum, int nchunk)
{
  const int lane = threadIdx.x;
  int v = (lane < nchunk) ? bsum[lane] : 0;
#pragma unroll
  for (int o = 1; o < 64; o <<= 1) {
    int u = __shfl_up(v, o, 64);
    if (lane >= o) v += u;
  }
  int ex = __shfl_up(v, 1, 64);
  if (lane == 0) ex = 0;
  if (lane < nchunk) bsum[lane] = ex;
}

__global__ __launch_bounds__(256) void scan3_kernel(
    int* __restrict__ off, const int* __restrict__ bsum, int* __restrict__ pos)
{
  int gid = blockIdx.x * 256 + threadIdx.x;
  if (gid <= N_NODES) {
    int v = off[gid] + bsum[gid >> 10];
    off[gid] = v;
    if (gid < N_NODES) pos[gid] = v;
  }
}

__global__ __launch_bounds__(256) void fill_kernel(
    const int* __restrict__ src, const int* __restrict__ dst,
    int* __restrict__ pos, int* __restrict__ csr_src)
{
  int e = blockIdx.x * 256 + threadIdx.x;
  if (e < N_EDGES) {
    int slot = atomicAdd(&pos[dst[e]], 1);
    csr_src[slot] = src[e];
  }
}

// ---------------- W -> bf16 ----------------
__global__ __launch_bounds__(256) void cvtw_kernel(
    const float* __restrict__ W1, const float* __restrict__ W2,
    unsigned short* __restrict__ W1b, unsigned short* __restrict__ W2b)
{
  int i = blockIdx.x * 256 + threadIdx.x;
  if (i < DIM * DIM) {
    W1b[i] = f2bf(W1[i]);
    W2b[i] = f2bf(W2[i]);
  }
}

// ---------------- gather (segment_sum via CSR) ----------------
__global__ __launch_bounds__(256) void gather_kernel(
    const float* __restrict__ y, const int* __restrict__ off,
    const int* __restrict__ csr_src, float* __restrict__ out)
{
  const int node = blockIdx.x * 4 + (threadIdx.x >> 6);
  if (node >= N_NODES) return;
  const int lane = threadIdx.x & 63;
  const int beg = off[node], end = off[node + 1];
  float2 a0 = {0.f, 0.f}, a1 = {0.f, 0.f};
  int j = beg;
  for (; j + 1 < end; j += 2) {
    int s0 = csr_src[j], s1 = csr_src[j + 1];
    float2 v0 = ((const float2*)(y + (size_t)s0 * DIM))[lane];
    float2 v1 = ((const float2*)(y + (size_t)s1 * DIM))[lane];
    a0.x += v0.x; a0.y += v0.y;
    a1.x += v1.x; a1.y += v1.y;
  }
  if (j < end) {
    int s0 = csr_src[j];
    float2 v0 = ((const float2*)(y + (size_t)s0 * DIM))[lane];
    a0.x += v0.x; a0.y += v0.y;
  }
  float2 r;
  r.x = a0.x + a1.x;
  r.y = a0.y + a1.y;
  ((float2*)(out + (size_t)node * DIM))[lane] = r;
}

// ---------------- fused logmap0 -> (W t + b via MFMA) -> expmap0 ----------------
// One block = 64-node tile. 4 waves; wave w owns nodes [tile*64+w*16, +16).
// W^T lives entirely in per-wave registers as 32 bf16 B-fragments.
__global__ __launch_bounds__(256, 2) void transform_mfma(
    const float* __restrict__ x, const unsigned short* __restrict__ Wb,
    const float* __restrict__ b, float* __restrict__ y, int relu_in)
{
  const int base = blockIdx.x * 64;
  const int tid = threadIdx.x;
  const int w = tid >> 6;
  const int l = tid & 63;
  const int lr = l & 15;   // A-row / B-col within tile
  const int lg = l >> 4;   // k-group 0..3

  __shared__ __align__(16) unsigned short At[64 * DIM];  // swizzled bf16 t-tile

  // B fragments: slot (lg, e) <- W^T[kc*32 + lg*8 + e][n*16+lr] = W[n*16+lr][kc*32+lg*8+e]
  bf16x8 bf[8][4];
#pragma unroll
  for (int n = 0; n < 8; ++n)
#pragma unroll
    for (int kc = 0; kc < 4; ++kc)
      bf[n][kc] = *(const bf16x8*)(Wb + (n * 16 + lr) * DIM + kc * 32 + lg * 8);

  float bias[8];
#pragma unroll
  for (int n = 0; n < 8; ++n) bias[n] = b[n * 16 + lr];

  // ---- logmap0: lane handles row lr of wave tile, cols lg*32..+31 ----
  const int row = w * 16 + lr;
  const int node = base + row;
  float v[32];
  if (node < N_NODES) {
    const float4* xr = (const float4*)(x + (size_t)node * DIM + lg * 32);
#pragma unroll
    for (int q = 0; q < 8; ++q) {
      float4 f = xr[q];
      v[q * 4 + 0] = f.x; v[q * 4 + 1] = f.y; v[q * 4 + 2] = f.z; v[q * 4 + 3] = f.w;
    }
  } else {
#pragma unroll
    for (int q = 0; q < 32; ++q) v[q] = 0.f;
  }
  if (relu_in) {
#pragma unroll
    for (int q = 0; q < 32; ++q) v[q] = fmaxf(v[q], 0.f);
  }
  float sq = 0.f;
#pragma unroll
  for (int q = 0; q < 32; ++q) sq += v[q] * v[q];
  sq += __shfl_xor(sq, 16, 64);
  sq += __shfl_xor(sq, 32, 64);
  float n1 = sqrtf(sq);
  float nc = fmaxf(n1, EPSF);
  float nm = fminf(nc, MAXNORM);
  float scale = 0.5f * logf((1.f + nm) / (1.f - nm)) / nc;

#pragma unroll
  for (int s = 0; s < 4; ++s) {
    unsigned short tmp[8];
#pragma unroll
    for (int e = 0; e < 8; ++e) tmp[e] = f2bf(v[s * 8 + e] * scale);
    int byte = row * 256 + lg * 64 + s * 16;
    byte ^= (row & 7) << 4;
    *(bf16x8*)((char*)At + byte) = *(const bf16x8*)tmp;
  }
  __syncthreads();

  // ---- MFMA: C[16 x 128] per wave ----
  f32x4 acc[8];
#pragma unroll
  for (int n = 0; n < 8; ++n) {
    acc[n][0] = bias[n]; acc[n][1] = bias[n]; acc[n][2] = bias[n]; acc[n][3] = bias[n];
  }
#pragma unroll
  for (int kc = 0; kc < 4; ++kc) {
    int arow = w * 16 + lr;
    int byte = arow * 256 + kc * 64 + lg * 16;
    byte ^= (arow & 7) << 4;
    bf16x8 af = *(const bf16x8*)((const char*)At + byte);
#pragma unroll
    for (int n = 0; n < 8; ++n)
      acc[n] = __builtin_amdgcn_mfma_f32_16x16x32_bf16(af, bf[n][kc], acc[n], 0, 0, 0);
  }

  // ---- expmap0 epilogue: lane holds rows lg*4+j, cols n*16+lr ----
  float rs[4];
#pragma unroll
  for (int j = 0; j < 4; ++j) {
    float s2 = 0.f;
#pragma unroll
    for (int n = 0; n < 8; ++n) s2 += acc[n][j] * acc[n][j];
    s2 += __shfl_xor(s2, 1, 64);
    s2 += __shfl_xor(s2, 2, 64);
    s2 += __shfl_xor(s2, 4, 64);
    s2 += __shfl_xor(s2, 8, 64);
    float n2 = sqrtf(s2);
    float n2c = fmaxf(n2, EPSF);
    rs[j] = tanhf(n2c) / n2c;
  }
#pragma unroll
  for (int j = 0; j < 4; ++j) {
    int nrow = base + w * 16 + lg * 4 + j;
    if (nrow < N_NODES) {
      float* yr = y + (size_t)nrow * DIM + lr;
#pragma unroll
      for (int n = 0; n < 8; ++n) yr[n * 16] = acc[n][j] * rs[j];
    }
  }
}

// ---------------- fused relu -> logmap0 -> t @ Wc^T + bc ----------------
__global__ __launch_bounds__(128) void classify_kernel(
    const float* __restrict__ h, const float* __restrict__ Wc,
    const float* __restrict__ bc, float* __restrict__ out)
{
  const int node = blockIdx.x;
  const int d = threadIdx.x;
  __shared__ float t[DIM];
  __shared__ float red[2];

  float v = fmaxf(h[(size_t)node * DIM + d], 0.0f);
  float s = waveSum(v * v);
  if ((d & 63) == 0) red[d >> 6] = s;
  __syncthreads();
  float n = sqrtf(red[0] + red[1]);
  float nc = fmaxf(n, EPSF);
  float nm = fminf(nc, MAXNORM);
  float scale = 0.5f * logf((1.0f + nm) / (1.0f - nm)) / nc;
  t[d] = v * scale;
  __syncthreads();

  const int lane = d & 63;
  const int wid = d >> 6;
  const float2 tl = ((const float2*)t)[lane];
  for (int c = wid; c < NCLS; c += 2) {
    const float2 w2 = ((const float2*)(Wc + (size_t)c * DIM))[lane];
    float p = tl.x * w2.x + tl.y * w2.y;
    p = waveSum(p);
    if (lane == 0) out[(size_t)node * NCLS + c] = p + bc[c];
  }
}

extern "C" void kernel_launch(void* const* d_in, const int* in_sizes, int n_in,
                              void* d_out, int out_size, void* d_ws, size_t ws_size,
                              hipStream_t stream)
{
  const int* edge = (const int*)d_in[0];
  const int* src = edge;            // edge_index[0]
  const int* dst = edge + N_EDGES;  // edge_index[1]
  const float* x  = (const float*)d_in[1];
  const float* W1 = (const float*)d_in[2];
  const float* b1 = (const float*)d_in[3];
  const float* W2 = (const float*)d_in[4];
  const float* b2 = (const float*)d_in[5];
  const float* Wc = (const float*)d_in[6];
  const float* bc = (const float*)d_in[7];
  float* out = (float*)d_out;

  float* bufA = (float*)d_ws;                          // transform output y
  float* bufB = bufA + (size_t)N_NODES * DIM;          // gather output h
  unsigned short* W1b = (unsigned short*)(bufB + (size_t)N_NODES * DIM);
  unsigned short* W2b = W1b + DIM * DIM;
  int* off  = (int*)(W2b + DIM * DIM);                 // 50001
  int* bsum = off + N_NODES + 4;                       // 64
  int* pos  = bsum + 64;                               // 50000
  int* csr  = pos + N_NODES;                           // 600000

  const int NCHUNK = (N_NODES + 1 + 1023) / 1024;  // 49
  const int NTILE = (N_NODES + 63) / 64;           // 782

  // --- CSR build (dst identical for both layers; build once) ---
  hipMemsetAsync(off, 0, (N_NODES + 1) * sizeof(int), stream);
  hist_kernel<<<(N_EDGES + 255) / 256, 256, 0, stream>>>(dst, off);
  scan1_kernel<<<NCHUNK, 1024, 0, stream>>>(off, bsum);
  scan2_kernel<<<1, 64, 0, stream>>>(bsum, NCHUNK);
  scan3_kernel<<<(N_NODES + 256) / 256, 256, 0, stream>>>(off, bsum, pos);
  fill_kernel<<<(N_EDGES + 255) / 256, 256, 0, stream>>>(src, dst, pos, csr);

  cvtw_kernel<<<(DIM * DIM + 255) / 256, 256, 0, stream>>>(W1, W2, W1b, W2b);

  // --- Layer 1 ---
  transform_mfma<<<NTILE, 256, 0, stream>>>(x, W1b, b1, bufA, 0);
  gather_kernel<<<(N_NODES + 3) / 4, 256, 0, stream>>>(bufA, off, csr, bufB);

  // --- Layer 2 (relu fused into input read) ---
  transform_mfma<<<NTILE, 256, 0, stream>>>(bufB, W2b, b2, bufA, 1);
  gather_kernel<<<(N_NODES + 3) / 4, 256, 0, stream>>>(bufA, off, csr, bufB);

  // --- Classifier (relu fused) ---
  classify_kernel<<<N_NODES, 128, 0, stream>>>(bufB, Wc, bc, out);
}

// Round 5
// 203.265 us; speedup vs baseline: 8.6068x; 1.4597x over previous
//
#include <hip/hip_runtime.h>

#define N_NODES 50000
#define N_EDGES 600000
#define DIM 128
#define NCLS 10
#define EPSF 1e-15f
#define MAXNORM 0.99999f  // 1 - 1e-5

typedef __attribute__((ext_vector_type(8))) short bf16x8;
typedef __attribute__((ext_vector_type(4))) float f32x4;

__device__ inline float waveSum(float v) {
#pragma unroll
  for (int o = 1; o < 64; o <<= 1) v += __shfl_xor(v, o, 64);
  return v;
}

__device__ inline unsigned short f2bf(float f) {
  union { float f; unsigned u; } c; c.f = f;
  return (unsigned short)((c.u + 0x7FFFu + ((c.u >> 16) & 1u)) >> 16);
}
__device__ inline float bf_lo(unsigned u) {  // low ushort -> float
  union { unsigned u; float f; } c; c.u = u << 16; return c.f;
}
__device__ inline float bf_hi(unsigned u) {  // high ushort -> float
  union { unsigned u; float f; } c; c.u = u & 0xFFFF0000u; return c.f;
}

// ---------------- CSR build ----------------

__global__ __launch_bounds__(256) void hist_kernel(
    const int* __restrict__ dst, int* __restrict__ off)
{
  int e = blockIdx.x * 256 + threadIdx.x;
  if (e < N_EDGES) atomicAdd(&off[dst[e] + 1], 1);
}

__global__ __launch_bounds__(1024) void scan1_kernel(
    int* __restrict__ off, int* __restrict__ bsum)
{
  const int gid = blockIdx.x * 1024 + threadIdx.x;
  const int lane = threadIdx.x & 63, wid = threadIdx.x >> 6;
  __shared__ int ws[16];
  int v = (gid <= N_NODES) ? off[gid] : 0;
#pragma unroll
  for (int o = 1; o < 64; o <<= 1) {
    int u = __shfl_up(v, o, 64);
    if (lane >= o) v += u;
  }
  if (lane == 63) ws[wid] = v;
  __syncthreads();
  if (wid == 0) {
    int z = (lane < 16) ? ws[lane] : 0;
#pragma unroll
    for (int o = 1; o < 16; o <<= 1) {
      int u = __shfl_up(z, o, 64);
      if (lane >= o) z += u;
    }
    if (lane < 16) ws[lane] = z;
  }
  __syncthreads();
  if (wid > 0) v += ws[wid - 1];
  if (gid <= N_NODES) off[gid] = v;
  if (threadIdx.x == 1023) bsum[blockIdx.x] = v;
}

__global__ __launch_bounds__(64) void scan2_kernel(int* __restrict__ bsum, int nchunk)
{
  const int lane = threadIdx.x;
  int v = (lane < nchunk) ? bsum[lane] : 0;
#pragma unroll
  for (int o = 1; o < 64; o <<= 1) {
    int u = __shfl_up(v, o, 64);
    if (lane >= o) v += u;
  }
  int ex = __shfl_up(v, 1, 64);
  if (lane == 0) ex = 0;
  if (lane < nchunk) bsum[lane] = ex;
}

__global__ __launch_bounds__(256) void scan3_kernel(
    int* __restrict__ off, const int* __restrict__ bsum, int* __restrict__ pos)
{
  int gid = blockIdx.x * 256 + threadIdx.x;
  if (gid <= N_NODES) {
    int v = off[gid] + bsum[gid >> 10];
    off[gid] = v;
    if (gid < N_NODES) pos[gid] = v;
  }
}

__global__ __launch_bounds__(256) void fill_kernel(
    const int* __restrict__ src, const int* __restrict__ dst,
    int* __restrict__ pos, int* __restrict__ csr_src)
{
  int e = blockIdx.x * 256 + threadIdx.x;
  if (e < N_EDGES) {
    int slot = atomicAdd(&pos[dst[e]], 1);
    csr_src[slot] = src[e];
  }
}

// ---------------- W -> bf16 ----------------
__global__ __launch_bounds__(256) void cvtw_kernel(
    const float* __restrict__ W1, const float* __restrict__ W2,
    unsigned short* __restrict__ W1b, unsigned short* __restrict__ W2b)
{
  int i = blockIdx.x * 256 + threadIdx.x;
  if (i < DIM * DIM) {
    W1b[i] = f2bf(W1[i]);
    W2b[i] = f2bf(W2[i]);
  }
}

// ---------------- gather (segment_sum via CSR), bf16 input -> f32 output ----------------
// One wave per destination node; 64 lanes x 2 bf16 (4B) = 256B row.
__global__ __launch_bounds__(256) void gather_kernel(
    const unsigned short* __restrict__ y, const int* __restrict__ off,
    const int* __restrict__ csr_src, float* __restrict__ out)
{
  const int node = blockIdx.x * 4 + (threadIdx.x >> 6);
  if (node >= N_NODES) return;
  const int lane = threadIdx.x & 63;
  const int beg = off[node], end = off[node + 1];
  float2 a0 = {0.f, 0.f}, a1 = {0.f, 0.f}, a2 = {0.f, 0.f}, a3 = {0.f, 0.f};
  int j = beg;
  for (; j + 3 < end; j += 4) {
    unsigned u0 = ((const unsigned*)(y + (size_t)csr_src[j    ] * DIM))[lane];
    unsigned u1 = ((const unsigned*)(y + (size_t)csr_src[j + 1] * DIM))[lane];
    unsigned u2 = ((const unsigned*)(y + (size_t)csr_src[j + 2] * DIM))[lane];
    unsigned u3 = ((const unsigned*)(y + (size_t)csr_src[j + 3] * DIM))[lane];
    a0.x += bf_lo(u0); a0.y += bf_hi(u0);
    a1.x += bf_lo(u1); a1.y += bf_hi(u1);
    a2.x += bf_lo(u2); a2.y += bf_hi(u2);
    a3.x += bf_lo(u3); a3.y += bf_hi(u3);
  }
  for (; j < end; ++j) {
    unsigned u0 = ((const unsigned*)(y + (size_t)csr_src[j] * DIM))[lane];
    a0.x += bf_lo(u0); a0.y += bf_hi(u0);
  }
  float2 r;
  r.x = (a0.x + a1.x) + (a2.x + a3.x);
  r.y = (a0.y + a1.y) + (a2.y + a3.y);
  ((float2*)(out + (size_t)node * DIM))[lane] = r;
}

// ---------------- gather + relu + logmap0 + Wc classifier (final layer) ----------------
__global__ __launch_bounds__(256) void gather_classify(
    const unsigned short* __restrict__ y, const int* __restrict__ off,
    const int* __restrict__ csr_src, const float* __restrict__ Wc,
    const float* __restrict__ bc, float* __restrict__ out)
{
  const int node = blockIdx.x * 4 + (threadIdx.x >> 6);
  if (node >= N_NODES) return;
  const int lane = threadIdx.x & 63;
  const int beg = off[node], end = off[node + 1];
  float2 a0 = {0.f, 0.f}, a1 = {0.f, 0.f}, a2 = {0.f, 0.f}, a3 = {0.f, 0.f};
  int j = beg;
  for (; j + 3 < end; j += 4) {
    unsigned u0 = ((const unsigned*)(y + (size_t)csr_src[j    ] * DIM))[lane];
    unsigned u1 = ((const unsigned*)(y + (size_t)csr_src[j + 1] * DIM))[lane];
    unsigned u2 = ((const unsigned*)(y + (size_t)csr_src[j + 2] * DIM))[lane];
    unsigned u3 = ((const unsigned*)(y + (size_t)csr_src[j + 3] * DIM))[lane];
    a0.x += bf_lo(u0); a0.y += bf_hi(u0);
    a1.x += bf_lo(u1); a1.y += bf_hi(u1);
    a2.x += bf_lo(u2); a2.y += bf_hi(u2);
    a3.x += bf_lo(u3); a3.y += bf_hi(u3);
  }
  for (; j < end; ++j) {
    unsigned u0 = ((const unsigned*)(y + (size_t)csr_src[j] * DIM))[lane];
    a0.x += bf_lo(u0); a0.y += bf_hi(u0);
  }
  float2 r;
  r.x = fmaxf((a0.x + a1.x) + (a2.x + a3.x), 0.f);  // relu
  r.y = fmaxf((a0.y + a1.y) + (a2.y + a3.y), 0.f);

  // logmap0 on the 128-dim row spread across the wave
  float s = waveSum(r.x * r.x + r.y * r.y);
  float n = sqrtf(s);
  float nc = fmaxf(n, EPSF);
  float nm = fminf(nc, MAXNORM);
  float scale = 0.5f * logf((1.0f + nm) / (1.0f - nm)) / nc;
  float2 t;
  t.x = r.x * scale;
  t.y = r.y * scale;

  // 10-class head: p_c = t . Wc[c] (+ bc)
  float outv = 0.f;
#pragma unroll
  for (int c = 0; c < NCLS; ++c) {
    float2 w2 = ((const float2*)(Wc + (size_t)c * DIM))[lane];
    float p = waveSum(t.x * w2.x + t.y * w2.y);
    if (lane == c) outv = p;
  }
  if (lane < NCLS) out[(size_t)node * NCLS + lane] = outv + bc[lane];
}

// ---------------- fused logmap0 -> (W t + b via MFMA) -> expmap0, bf16 output ----------------
// One block = 64-node tile. 4 waves; wave w owns nodes [tile*64+w*16, +16).
// W^T lives entirely in per-wave registers as 32 bf16 B-fragments.
__global__ __launch_bounds__(256, 2) void transform_mfma(
    const float* __restrict__ x, const unsigned short* __restrict__ Wb,
    const float* __restrict__ b, unsigned short* __restrict__ y, int relu_in)
{
  const int base = blockIdx.x * 64;
  const int tid = threadIdx.x;
  const int w = tid >> 6;
  const int l = tid & 63;
  const int lr = l & 15;   // A-row / B-col within tile
  const int lg = l >> 4;   // k-group 0..3

  __shared__ __align__(16) unsigned short At[64 * DIM];  // swizzled bf16 t-tile

  // B fragments: slot (lg, e) <- W^T[kc*32 + lg*8 + e][n*16+lr] = W[n*16+lr][kc*32+lg*8+e]
  bf16x8 bf[8][4];
#pragma unroll
  for (int n = 0; n < 8; ++n)
#pragma unroll
    for (int kc = 0; kc < 4; ++kc)
      bf[n][kc] = *(const bf16x8*)(Wb + (n * 16 + lr) * DIM + kc * 32 + lg * 8);

  float bias[8];
#pragma unroll
  for (int n = 0; n < 8; ++n) bias[n] = b[n * 16 + lr];

  // ---- logmap0: lane handles row lr of wave tile, cols lg*32..+31 ----
  const int row = w * 16 + lr;
  const int node = base + row;
  float v[32];
  if (node < N_NODES) {
    const float4* xr = (const float4*)(x + (size_t)node * DIM + lg * 32);
#pragma unroll
    for (int q = 0; q < 8; ++q) {
      float4 f = xr[q];
      v[q * 4 + 0] = f.x; v[q * 4 + 1] = f.y; v[q * 4 + 2] = f.z; v[q * 4 + 3] = f.w;
    }
  } else {
#pragma unroll
    for (int q = 0; q < 32; ++q) v[q] = 0.f;
  }
  if (relu_in) {
#pragma unroll
    for (int q = 0; q < 32; ++q) v[q] = fmaxf(v[q], 0.f);
  }
  float sq = 0.f;
#pragma unroll
  for (int q = 0; q < 32; ++q) sq += v[q] * v[q];
  sq += __shfl_xor(sq, 16, 64);
  sq += __shfl_xor(sq, 32, 64);
  float n1 = sqrtf(sq);
  float nc = fmaxf(n1, EPSF);
  float nm = fminf(nc, MAXNORM);
  float scale = 0.5f * logf((1.f + nm) / (1.f - nm)) / nc;

#pragma unroll
  for (int s = 0; s < 4; ++s) {
    unsigned short tmp[8];
#pragma unroll
    for (int e = 0; e < 8; ++e) tmp[e] = f2bf(v[s * 8 + e] * scale);
    int byte = row * 256 + lg * 64 + s * 16;
    byte ^= (row & 7) << 4;
    *(bf16x8*)((char*)At + byte) = *(const bf16x8*)tmp;
  }
  __syncthreads();

  // ---- MFMA: C[16 x 128] per wave ----
  f32x4 acc[8];
#pragma unroll
  for (int n = 0; n < 8; ++n) {
    acc[n][0] = bias[n]; acc[n][1] = bias[n]; acc[n][2] = bias[n]; acc[n][3] = bias[n];
  }
#pragma unroll
  for (int kc = 0; kc < 4; ++kc) {
    int arow = w * 16 + lr;
    int byte = arow * 256 + kc * 64 + lg * 16;
    byte ^= (arow & 7) << 4;
    bf16x8 af = *(const bf16x8*)((const char*)At + byte);
#pragma unroll
    for (int n = 0; n < 8; ++n)
      acc[n] = __builtin_amdgcn_mfma_f32_16x16x32_bf16(af, bf[n][kc], acc[n], 0, 0, 0);
  }

  // ---- expmap0 epilogue: lane holds rows lg*4+j, cols n*16+lr ----
  float rs[4];
#pragma unroll
  for (int j = 0; j < 4; ++j) {
    float s2 = 0.f;
#pragma unroll
    for (int n = 0; n < 8; ++n) s2 += acc[n][j] * acc[n][j];
    s2 += __shfl_xor(s2, 1, 64);
    s2 += __shfl_xor(s2, 2, 64);
    s2 += __shfl_xor(s2, 4, 64);
    s2 += __shfl_xor(s2, 8, 64);
    float n2 = sqrtf(s2);
    float n2c = fmaxf(n2, EPSF);
    rs[j] = tanhf(n2c) / n2c;
  }
#pragma unroll
  for (int j = 0; j < 4; ++j) {
    int nrow = base + w * 16 + lg * 4 + j;
    if (nrow < N_NODES) {
      unsigned short* yr = y + (size_t)nrow * DIM + lr;
#pragma unroll
      for (int n = 0; n < 8; ++n) yr[n * 16] = f2bf(acc[n][j] * rs[j]);
    }
  }
}

extern "C" void kernel_launch(void* const* d_in, const int* in_sizes, int n_in,
                              void* d_out, int out_size, void* d_ws, size_t ws_size,
                              hipStream_t stream)
{
  const int* edge = (const int*)d_in[0];
  const int* src = edge;            // edge_index[0]
  const int* dst = edge + N_EDGES;  // edge_index[1]
  const float* x  = (const float*)d_in[1];
  const float* W1 = (const float*)d_in[2];
  const float* b1 = (const float*)d_in[3];
  const float* W2 = (const float*)d_in[4];
  const float* b2 = (const float*)d_in[5];
  const float* Wc = (const float*)d_in[6];
  const float* bc = (const float*)d_in[7];
  float* out = (float*)d_out;

  unsigned short* ybuf = (unsigned short*)d_ws;        // bf16 transform output [N, D]
  float* hbuf = (float*)(ybuf + (size_t)N_NODES * DIM);  // f32 gather output [N, D]
  unsigned short* W1b = (unsigned short*)(hbuf + (size_t)N_NODES * DIM);
  unsigned short* W2b = W1b + DIM * DIM;
  int* off  = (int*)(W2b + DIM * DIM);                 // 50001
  int* bsum = off + N_NODES + 4;                       // 64
  int* pos  = bsum + 64;                               // 50000
  int* csr  = pos + N_NODES;                           // 600000

  const int NCHUNK = (N_NODES + 1 + 1023) / 1024;  // 49
  const int NTILE = (N_NODES + 63) / 64;           // 782

  // --- CSR build (dst identical for both layers; build once) ---
  hipMemsetAsync(off, 0, (N_NODES + 1) * sizeof(int), stream);
  hist_kernel<<<(N_EDGES + 255) / 256, 256, 0, stream>>>(dst, off);
  scan1_kernel<<<NCHUNK, 1024, 0, stream>>>(off, bsum);
  scan2_kernel<<<1, 64, 0, stream>>>(bsum, NCHUNK);
  scan3_kernel<<<(N_NODES + 256) / 256, 256, 0, stream>>>(off, bsum, pos);
  fill_kernel<<<(N_EDGES + 255) / 256, 256, 0, stream>>>(src, dst, pos, csr);

  cvtw_kernel<<<(DIM * DIM + 255) / 256, 256, 0, stream>>>(W1, W2, W1b, W2b);

  // --- Layer 1 ---
  transform_mfma<<<NTILE, 256, 0, stream>>>(x, W1b, b1, ybuf, 0);
  gather_kernel<<<(N_NODES + 3) / 4, 256, 0, stream>>>(ybuf, off, csr, hbuf);

  // --- Layer 2 (relu fused into transform input read) ---
  transform_mfma<<<NTILE, 256, 0, stream>>>(hbuf, W2b, b2, ybuf, 1);

  // --- Final gather + relu + logmap0 + classifier ---
  gather_classify<<<(N_NODES + 3) / 4, 256, 0, stream>>>(ybuf, off, csr, Wc, bc, out);
}

// Round 6
// 199.450 us; speedup vs baseline: 8.7714x; 1.0191x over previous
//
#include <hip/hip_runtime.h>

#define N_NODES 50000
#define N_EDGES 600000
#define DIM 128
#define NCLS 10
#define EPSF 1e-15f
#define MAXNORM 0.99999f  // 1 - 1e-5

typedef __attribute__((ext_vector_type(8))) short bf16x8;
typedef __attribute__((ext_vector_type(4))) float f32x4;

__device__ inline float waveSum(float v) {
#pragma unroll
  for (int o = 1; o < 64; o <<= 1) v += __shfl_xor(v, o, 64);
  return v;
}

__device__ inline unsigned short f2bf(float f) {
  union { float f; unsigned u; } c; c.f = f;
  return (unsigned short)((c.u + 0x7FFFu + ((c.u >> 16) & 1u)) >> 16);
}
__device__ inline float bf_lo(unsigned u) {
  union { unsigned u; float f; } c; c.u = u << 16; return c.f;
}
__device__ inline float bf_hi(unsigned u) {
  union { unsigned u; float f; } c; c.u = u & 0xFFFF0000u; return c.f;
}

// ---------------- CSR build ----------------

__global__ __launch_bounds__(256) void hist_kernel(
    const int* __restrict__ dst, int* __restrict__ off)
{
  int e = blockIdx.x * 256 + threadIdx.x;
  if (e < N_EDGES) atomicAdd(&off[dst[e] + 1], 1);
}

__global__ __launch_bounds__(1024) void scan1_kernel(
    int* __restrict__ off, int* __restrict__ bsum)
{
  const int gid = blockIdx.x * 1024 + threadIdx.x;
  const int lane = threadIdx.x & 63, wid = threadIdx.x >> 6;
  __shared__ int ws[16];
  int v = (gid <= N_NODES) ? off[gid] : 0;
#pragma unroll
  for (int o = 1; o < 64; o <<= 1) {
    int u = __shfl_up(v, o, 64);
    if (lane >= o) v += u;
  }
  if (lane == 63) ws[wid] = v;
  __syncthreads();
  if (wid == 0) {
    int z = (lane < 16) ? ws[lane] : 0;
#pragma unroll
    for (int o = 1; o < 16; o <<= 1) {
      int u = __shfl_up(z, o, 64);
      if (lane >= o) z += u;
    }
    if (lane < 16) ws[lane] = z;
  }
  __syncthreads();
  if (wid > 0) v += ws[wid - 1];
  if (gid <= N_NODES) off[gid] = v;
  if (threadIdx.x == 1023) bsum[blockIdx.x] = v;
}

__global__ __launch_bounds__(64) void scan2_kernel(int* __restrict__ bsum, int nchunk)
{
  const int lane = threadIdx.x;
  int v = (lane < nchunk) ? bsum[lane] : 0;
#pragma unroll
  for (int o = 1; o < 64; o <<= 1) {
    int u = __shfl_up(v, o, 64);
    if (lane >= o) v += u;
  }
  int ex = __shfl_up(v, 1, 64);
  if (lane == 0) ex = 0;
  if (lane < nchunk) bsum[lane] = ex;
}

__global__ __launch_bounds__(256) void scan3_kernel(
    int* __restrict__ off, const int* __restrict__ bsum, int* __restrict__ pos)
{
  int gid = blockIdx.x * 256 + threadIdx.x;
  if (gid <= N_NODES) {
    int v = off[gid] + bsum[gid >> 10];
    off[gid] = v;
    if (gid < N_NODES) pos[gid] = v;
  }
}

__global__ __launch_bounds__(256) void fill_kernel(
    const int* __restrict__ src, const int* __restrict__ dst,
    int* __restrict__ pos, int* __restrict__ csr_src)
{
  int e = blockIdx.x * 256 + threadIdx.x;
  if (e < N_EDGES) {
    int slot = atomicAdd(&pos[dst[e]], 1);
    csr_src[slot] = src[e];
  }
}

// ---------------- W -> bf16 ----------------
__global__ __launch_bounds__(256) void cvtw_kernel(
    const float* __restrict__ W1, const float* __restrict__ W2,
    unsigned short* __restrict__ W1b, unsigned short* __restrict__ W2b)
{
  int i = blockIdx.x * 256 + threadIdx.x;
  if (i < DIM * DIM) {
    W1b[i] = f2bf(W1[i]);
    W2b[i] = f2bf(W2[i]);
  }
}

// ---------------- gather + relu + logmap0 -> bf16 tangent ----------------
// One wave per destination node; 64 lanes x 2 bf16 (4B) = 256B row.
__global__ __launch_bounds__(256) void gatherT_kernel(
    const unsigned short* __restrict__ y, const int* __restrict__ off,
    const int* __restrict__ csr_src, unsigned short* __restrict__ tout)
{
  const int node = blockIdx.x * 4 + (threadIdx.x >> 6);
  if (node >= N_NODES) return;
  const int lane = threadIdx.x & 63;
  const int beg = off[node], end = off[node + 1];
  float2 a0 = {0.f, 0.f}, a1 = {0.f, 0.f}, a2 = {0.f, 0.f}, a3 = {0.f, 0.f};
  int j = beg;
  for (; j + 3 < end; j += 4) {
    unsigned u0 = ((const unsigned*)(y + (size_t)csr_src[j    ] * DIM))[lane];
    unsigned u1 = ((const unsigned*)(y + (size_t)csr_src[j + 1] * DIM))[lane];
    unsigned u2 = ((const unsigned*)(y + (size_t)csr_src[j + 2] * DIM))[lane];
    unsigned u3 = ((const unsigned*)(y + (size_t)csr_src[j + 3] * DIM))[lane];
    a0.x += bf_lo(u0); a0.y += bf_hi(u0);
    a1.x += bf_lo(u1); a1.y += bf_hi(u1);
    a2.x += bf_lo(u2); a2.y += bf_hi(u2);
    a3.x += bf_lo(u3); a3.y += bf_hi(u3);
  }
  for (; j < end; ++j) {
    unsigned u0 = ((const unsigned*)(y + (size_t)csr_src[j] * DIM))[lane];
    a0.x += bf_lo(u0); a0.y += bf_hi(u0);
  }
  float2 r;
  r.x = fmaxf((a0.x + a1.x) + (a2.x + a3.x), 0.f);  // relu
  r.y = fmaxf((a0.y + a1.y) + (a2.y + a3.y), 0.f);

  // logmap0 across the wave-held 128-dim row
  float s = waveSum(r.x * r.x + r.y * r.y);
  float n = sqrtf(s);
  float nc = fmaxf(n, EPSF);
  float nm = fminf(nc, MAXNORM);
  float scale = 0.5f * logf((1.0f + nm) / (1.0f - nm)) / nc;
  unsigned u = (unsigned)f2bf(r.x * scale) | ((unsigned)f2bf(r.y * scale) << 16);
  ((unsigned*)(tout + (size_t)node * DIM))[lane] = u;
}

// ---------------- fused (logmap0?) -> (W t + b via MFMA) -> expmap0, bf16 out ------
// MODE 0: input f32 on manifold (apply logmap0). MODE 1: input bf16 tangent (direct).
// One block = 64-node tile, 4 waves; wave w owns nodes [tile*64+w*16, +16).
// W^T entirely in per-wave registers as 32 bf16 B-fragments.
template <int MODE>
__global__ __launch_bounds__(256, 2) void transform_mfma(
    const void* __restrict__ xin, const unsigned short* __restrict__ Wb,
    const float* __restrict__ b, unsigned short* __restrict__ y)
{
  const int base = blockIdx.x * 64;
  const int tid = threadIdx.x;
  const int w = tid >> 6;
  const int l = tid & 63;
  const int lr = l & 15;   // A-row / B-col within tile
  const int lg = l >> 4;   // k-group 0..3

  __shared__ __align__(16) unsigned short At[64 * DIM];  // swizzled bf16 t-tile

  // B fragments: slot (lg, e) <- W[n*16+lr][kc*32 + lg*8 + e]
  bf16x8 bf[8][4];
#pragma unroll
  for (int n = 0; n < 8; ++n)
#pragma unroll
    for (int kc = 0; kc < 4; ++kc)
      bf[n][kc] = *(const bf16x8*)(Wb + (n * 16 + lr) * DIM + kc * 32 + lg * 8);

  float bias[8];
#pragma unroll
  for (int n = 0; n < 8; ++n) bias[n] = b[n * 16 + lr];

  const int row = w * 16 + lr;
  const int node = base + row;

  if (MODE == 0) {
    // ---- logmap0: lane handles row lr, cols lg*32..+31 ----
    const float* x = (const float*)xin;
    float v[32];
    if (node < N_NODES) {
      const float4* xr = (const float4*)(x + (size_t)node * DIM + lg * 32);
#pragma unroll
      for (int q = 0; q < 8; ++q) {
        float4 f = xr[q];
        v[q * 4 + 0] = f.x; v[q * 4 + 1] = f.y; v[q * 4 + 2] = f.z; v[q * 4 + 3] = f.w;
      }
    } else {
#pragma unroll
      for (int q = 0; q < 32; ++q) v[q] = 0.f;
    }
    float sq = 0.f;
#pragma unroll
    for (int q = 0; q < 32; ++q) sq += v[q] * v[q];
    sq += __shfl_xor(sq, 16, 64);
    sq += __shfl_xor(sq, 32, 64);
    float n1 = sqrtf(sq);
    float nc = fmaxf(n1, EPSF);
    float nm = fminf(nc, MAXNORM);
    float scale = 0.5f * logf((1.f + nm) / (1.f - nm)) / nc;
#pragma unroll
    for (int s = 0; s < 4; ++s) {
      unsigned short tmp[8];
#pragma unroll
      for (int e = 0; e < 8; ++e) tmp[e] = f2bf(v[s * 8 + e] * scale);
      int byte = row * 256 + lg * 64 + s * 16;
      byte ^= (row & 7) << 4;
      *(bf16x8*)((char*)At + byte) = *(const bf16x8*)tmp;
    }
  } else {
    // ---- input is bf16 tangent: straight copy into swizzled LDS ----
    const unsigned short* t = (const unsigned short*)xin;
#pragma unroll
    for (int s = 0; s < 4; ++s) {
      bf16x8 frag;
      if (node < N_NODES)
        frag = *(const bf16x8*)(t + (size_t)node * DIM + lg * 32 + s * 8);
      else
        frag = bf16x8{0, 0, 0, 0, 0, 0, 0, 0};
      int byte = row * 256 + lg * 64 + s * 16;
      byte ^= (row & 7) << 4;
      *(bf16x8*)((char*)At + byte) = frag;
    }
  }
  __syncthreads();

  // ---- MFMA: C[16 x 128] per wave ----
  f32x4 acc[8];
#pragma unroll
  for (int n = 0; n < 8; ++n) {
    acc[n][0] = bias[n]; acc[n][1] = bias[n]; acc[n][2] = bias[n]; acc[n][3] = bias[n];
  }
#pragma unroll
  for (int kc = 0; kc < 4; ++kc) {
    int arow = w * 16 + lr;
    int byte = arow * 256 + kc * 64 + lg * 16;
    byte ^= (arow & 7) << 4;
    bf16x8 af = *(const bf16x8*)((const char*)At + byte);
#pragma unroll
    for (int n = 0; n < 8; ++n)
      acc[n] = __builtin_amdgcn_mfma_f32_16x16x32_bf16(af, bf[n][kc], acc[n], 0, 0, 0);
  }

  // ---- expmap0 epilogue: lane holds rows lg*4+j, cols n*16+lr ----
  float rs[4];
#pragma unroll
  for (int j = 0; j < 4; ++j) {
    float s2 = 0.f;
#pragma unroll
    for (int n = 0; n < 8; ++n) s2 += acc[n][j] * acc[n][j];
    s2 += __shfl_xor(s2, 1, 64);
    s2 += __shfl_xor(s2, 2, 64);
    s2 += __shfl_xor(s2, 4, 64);
    s2 += __shfl_xor(s2, 8, 64);
    float n2 = sqrtf(s2);
    float n2c = fmaxf(n2, EPSF);
    rs[j] = tanhf(n2c) / n2c;
  }
#pragma unroll
  for (int j = 0; j < 4; ++j) {
    int nrow = base + w * 16 + lg * 4 + j;
    if (nrow < N_NODES) {
      unsigned short* yr = y + (size_t)nrow * DIM + lr;
#pragma unroll
      for (int n = 0; n < 8; ++n) yr[n * 16] = f2bf(acc[n][j] * rs[j]);
    }
  }
}

// ---------------- classifier head: out = t2 @ Wc^T + bc via MFMA ----------------
// One wave per 16 nodes; K=128 via 4x mfma 16x16x32; N=16 (cols 10..15 unused).
__global__ __launch_bounds__(256) void head_mfma(
    const unsigned short* __restrict__ t2, const float* __restrict__ Wc,
    const float* __restrict__ bc, float* __restrict__ out)
{
  const int base = blockIdx.x * 64;
  const int w = threadIdx.x >> 6;
  const int l = threadIdx.x & 63;
  const int lr = l & 15;
  const int lg = l >> 4;

  // B fragments from Wc (f32 -> bf16 on the fly); rows >= NCLS are zero.
  bf16x8 bw[4];
#pragma unroll
  for (int kc = 0; kc < 4; ++kc) {
    unsigned short tmp[8];
    if (lr < NCLS) {
      const float* wr = Wc + (size_t)lr * DIM + kc * 32 + lg * 8;
#pragma unroll
      for (int e = 0; e < 8; ++e) tmp[e] = f2bf(wr[e]);
    } else {
#pragma unroll
      for (int e = 0; e < 8; ++e) tmp[e] = 0;
    }
    bw[kc] = *(const bf16x8*)tmp;
  }
  const float bias = (lr < NCLS) ? bc[lr] : 0.f;

  const int arow = base + w * 16 + lr;
  f32x4 acc;
  acc[0] = bias; acc[1] = bias; acc[2] = bias; acc[3] = bias;
#pragma unroll
  for (int kc = 0; kc < 4; ++kc) {
    bf16x8 af;
    if (arow < N_NODES)
      af = *(const bf16x8*)(t2 + (size_t)arow * DIM + kc * 32 + lg * 8);
    else
      af = bf16x8{0, 0, 0, 0, 0, 0, 0, 0};
    acc = __builtin_amdgcn_mfma_f32_16x16x32_bf16(af, bw[kc], acc, 0, 0, 0);
  }

  // C layout: col = lr (class), row = lg*4 + j (node within 16)
  if (lr < NCLS) {
#pragma unroll
    for (int j = 0; j < 4; ++j) {
      int nrow = base + w * 16 + lg * 4 + j;
      if (nrow < N_NODES) out[(size_t)nrow * NCLS + lr] = acc[j];
    }
  }
}

extern "C" void kernel_launch(void* const* d_in, const int* in_sizes, int n_in,
                              void* d_out, int out_size, void* d_ws, size_t ws_size,
                              hipStream_t stream)
{
  const int* edge = (const int*)d_in[0];
  const int* src = edge;            // edge_index[0]
  const int* dst = edge + N_EDGES;  // edge_index[1]
  const float* x  = (const float*)d_in[1];
  const float* W1 = (const float*)d_in[2];
  const float* b1 = (const float*)d_in[3];
  const float* W2 = (const float*)d_in[4];
  const float* b2 = (const float*)d_in[5];
  const float* Wc = (const float*)d_in[6];
  const float* bc = (const float*)d_in[7];
  float* out = (float*)d_out;

  unsigned short* ybuf = (unsigned short*)d_ws;          // bf16 y [N, D]
  unsigned short* tbuf = ybuf + (size_t)N_NODES * DIM;   // bf16 tangent [N, D]
  unsigned short* W1b = tbuf + (size_t)N_NODES * DIM;
  unsigned short* W2b = W1b + DIM * DIM;
  int* off  = (int*)(W2b + DIM * DIM);                 // 50001
  int* bsum = off + N_NODES + 4;                       // 64
  int* pos  = bsum + 64;                               // 50000
  int* csr  = pos + N_NODES;                           // 600000

  const int NCHUNK = (N_NODES + 1 + 1023) / 1024;  // 49
  const int NTILE = (N_NODES + 63) / 64;           // 782

  // --- CSR build (dst identical for both layers; build once) ---
  hipMemsetAsync(off, 0, (N_NODES + 1) * sizeof(int), stream);
  hist_kernel<<<(N_EDGES + 255) / 256, 256, 0, stream>>>(dst, off);
  scan1_kernel<<<NCHUNK, 1024, 0, stream>>>(off, bsum);
  scan2_kernel<<<1, 64, 0, stream>>>(bsum, NCHUNK);
  scan3_kernel<<<(N_NODES + 256) / 256, 256, 0, stream>>>(off, bsum, pos);
  fill_kernel<<<(N_EDGES + 255) / 256, 256, 0, stream>>>(src, dst, pos, csr);

  cvtw_kernel<<<(DIM * DIM + 255) / 256, 256, 0, stream>>>(W1, W2, W1b, W2b);

  // --- Layer 1: x (f32, manifold) -> y1 (bf16) ---
  transform_mfma<0><<<NTILE, 256, 0, stream>>>(x, W1b, b1, ybuf);
  // --- gather + relu + logmap -> t (bf16) ---
  gatherT_kernel<<<(N_NODES + 3) / 4, 256, 0, stream>>>(ybuf, off, csr, tbuf);

  // --- Layer 2: t (bf16 tangent) -> y2 (bf16) ---
  transform_mfma<1><<<NTILE, 256, 0, stream>>>(tbuf, W2b, b2, ybuf);
  // --- gather + relu + logmap -> t2 (bf16) ---
  gatherT_kernel<<<(N_NODES + 3) / 4, 256, 0, stream>>>(ybuf, off, csr, tbuf);

  // --- classifier head ---
  head_mfma<<<NTILE, 256, 0, stream>>>(tbuf, Wc, bc, out);
}

// Round 7
// 196.981 us; speedup vs baseline: 8.8813x; 1.0125x over previous
//
#include <hip/hip_runtime.h>

#define N_NODES 50000
#define N_EDGES 600000
#define DIM 128
#define NCLS 10
#define EPSF 1e-15f
#define MAXNORM 0.99999f  // 1 - 1e-5

typedef __attribute__((ext_vector_type(8))) short bf16x8;
typedef __attribute__((ext_vector_type(4))) float f32x4;

__device__ inline float waveSum(float v) {
#pragma unroll
  for (int o = 1; o < 64; o <<= 1) v += __shfl_xor(v, o, 64);
  return v;
}

__device__ inline unsigned short f2bf(float f) {
  union { float f; unsigned u; } c; c.f = f;
  return (unsigned short)((c.u + 0x7FFFu + ((c.u >> 16) & 1u)) >> 16);
}
__device__ inline float bf_lo(unsigned u) {
  union { unsigned u; float f; } c; c.u = u << 16; return c.f;
}
__device__ inline float bf_hi(unsigned u) {
  union { unsigned u; float f; } c; c.u = u & 0xFFFF0000u; return c.f;
}

// ---------------- init: zero CSR offsets + convert W1/W2 to bf16 ----------------
__global__ __launch_bounds__(256) void init_kernel(
    int* __restrict__ off, const float* __restrict__ W1, const float* __restrict__ W2,
    unsigned short* __restrict__ W1b, unsigned short* __restrict__ W2b)
{
  int i = blockIdx.x * 256 + threadIdx.x;
  if (i <= N_NODES) off[i] = 0;
  if (i < DIM * DIM) {
    W1b[i] = f2bf(W1[i]);
    W2b[i] = f2bf(W2[i]);
  }
}

// ---------------- CSR build ----------------

__global__ __launch_bounds__(256) void hist_kernel(
    const int* __restrict__ dst, int* __restrict__ off)
{
  int e = blockIdx.x * 256 + threadIdx.x;
  if (e < N_EDGES) atomicAdd(&off[dst[e] + 1], 1);
}

__global__ __launch_bounds__(1024) void scan1_kernel(
    int* __restrict__ off, int* __restrict__ bsum)
{
  const int gid = blockIdx.x * 1024 + threadIdx.x;
  const int lane = threadIdx.x & 63, wid = threadIdx.x >> 6;
  __shared__ int ws[16];
  int v = (gid <= N_NODES) ? off[gid] : 0;
#pragma unroll
  for (int o = 1; o < 64; o <<= 1) {
    int u = __shfl_up(v, o, 64);
    if (lane >= o) v += u;
  }
  if (lane == 63) ws[wid] = v;
  __syncthreads();
  if (wid == 0) {
    int z = (lane < 16) ? ws[lane] : 0;
#pragma unroll
    for (int o = 1; o < 16; o <<= 1) {
      int u = __shfl_up(z, o, 64);
      if (lane >= o) z += u;
    }
    if (lane < 16) ws[lane] = z;
  }
  __syncthreads();
  if (wid > 0) v += ws[wid - 1];
  if (gid <= N_NODES) off[gid] = v;
  if (threadIdx.x == 1023) bsum[blockIdx.x] = v;
}

__global__ __launch_bounds__(64) void scan2_kernel(int* __restrict__ bsum, int nchunk)
{
  const int lane = threadIdx.x;
  int v = (lane < nchunk) ? bsum[lane] : 0;
#pragma unroll
  for (int o = 1; o < 64; o <<= 1) {
    int u = __shfl_up(v, o, 64);
    if (lane >= o) v += u;
  }
  int ex = __shfl_up(v, 1, 64);
  if (lane == 0) ex = 0;
  if (lane < nchunk) bsum[lane] = ex;
}

__global__ __launch_bounds__(256) void scan3_kernel(
    int* __restrict__ off, const int* __restrict__ bsum, int* __restrict__ pos)
{
  int gid = blockIdx.x * 256 + threadIdx.x;
  if (gid <= N_NODES) {
    int v = off[gid] + bsum[gid >> 10];
    off[gid] = v;
    if (gid < N_NODES) pos[gid] = v;
  }
}

__global__ __launch_bounds__(256) void fill_kernel(
    const int* __restrict__ src, const int* __restrict__ dst,
    int* __restrict__ pos, int* __restrict__ csr_src)
{
  int e = blockIdx.x * 256 + threadIdx.x;
  if (e < N_EDGES) {
    int slot = atomicAdd(&pos[dst[e]], 1);
    csr_src[slot] = src[e];
  }
}

// ---------------- gather + relu + logmap0 -> bf16 tangent ----------------
// One wave per destination node; 64 lanes x 2 bf16 (4B) = 256B row.
__global__ __launch_bounds__(256) void gatherT_kernel(
    const unsigned short* __restrict__ y, const int* __restrict__ off,
    const int* __restrict__ csr_src, unsigned short* __restrict__ tout)
{
  const int node = blockIdx.x * 4 + (threadIdx.x >> 6);
  if (node >= N_NODES) return;
  const int lane = threadIdx.x & 63;
  const int beg = off[node], end = off[node + 1];
  float2 a0 = {0.f, 0.f}, a1 = {0.f, 0.f}, a2 = {0.f, 0.f}, a3 = {0.f, 0.f};
  int j = beg;
  for (; j + 3 < end; j += 4) {
    unsigned u0 = ((const unsigned*)(y + (size_t)csr_src[j    ] * DIM))[lane];
    unsigned u1 = ((const unsigned*)(y + (size_t)csr_src[j + 1] * DIM))[lane];
    unsigned u2 = ((const unsigned*)(y + (size_t)csr_src[j + 2] * DIM))[lane];
    unsigned u3 = ((const unsigned*)(y + (size_t)csr_src[j + 3] * DIM))[lane];
    a0.x += bf_lo(u0); a0.y += bf_hi(u0);
    a1.x += bf_lo(u1); a1.y += bf_hi(u1);
    a2.x += bf_lo(u2); a2.y += bf_hi(u2);
    a3.x += bf_lo(u3); a3.y += bf_hi(u3);
  }
  for (; j < end; ++j) {
    unsigned u0 = ((const unsigned*)(y + (size_t)csr_src[j] * DIM))[lane];
    a0.x += bf_lo(u0); a0.y += bf_hi(u0);
  }
  float2 r;
  r.x = fmaxf((a0.x + a1.x) + (a2.x + a3.x), 0.f);  // relu
  r.y = fmaxf((a0.y + a1.y) + (a2.y + a3.y), 0.f);

  // logmap0 across the wave-held 128-dim row
  float s = waveSum(r.x * r.x + r.y * r.y);
  float n = sqrtf(s);
  float nc = fmaxf(n, EPSF);
  float nm = fminf(nc, MAXNORM);
  float scale = 0.5f * logf((1.0f + nm) / (1.0f - nm)) / nc;
  unsigned u = (unsigned)f2bf(r.x * scale) | ((unsigned)f2bf(r.y * scale) << 16);
  ((unsigned*)(tout + (size_t)node * DIM))[lane] = u;
}

// ---------------- fused (logmap0?) -> (W t + b via MFMA) -> expmap0, bf16 out ------
// MODE 0: input f32 on manifold (apply logmap0). MODE 1: input bf16 tangent (direct).
// One block = 64-node tile, 4 waves; wave w owns nodes [tile*64+w*16, +16).
// W^T entirely in per-wave registers as 32 bf16 B-fragments.
template <int MODE>
__global__ __launch_bounds__(256, 2) void transform_mfma(
    const void* __restrict__ xin, const unsigned short* __restrict__ Wb,
    const float* __restrict__ b, unsigned short* __restrict__ y)
{
  const int base = blockIdx.x * 64;
  const int tid = threadIdx.x;
  const int w = tid >> 6;
  const int l = tid & 63;
  const int lr = l & 15;   // A-row / B-col within tile
  const int lg = l >> 4;   // k-group 0..3

  __shared__ __align__(16) unsigned short At[64 * DIM];  // swizzled bf16 t-tile

  // B fragments: slot (lg, e) <- W[n*16+lr][kc*32 + lg*8 + e]
  bf16x8 bf[8][4];
#pragma unroll
  for (int n = 0; n < 8; ++n)
#pragma unroll
    for (int kc = 0; kc < 4; ++kc)
      bf[n][kc] = *(const bf16x8*)(Wb + (n * 16 + lr) * DIM + kc * 32 + lg * 8);

  float bias[8];
#pragma unroll
  for (int n = 0; n < 8; ++n) bias[n] = b[n * 16 + lr];

  const int row = w * 16 + lr;
  const int node = base + row;

  if (MODE == 0) {
    // ---- logmap0: lane handles row lr, cols lg*32..+31 ----
    const float* x = (const float*)xin;
    float v[32];
    if (node < N_NODES) {
      const float4* xr = (const float4*)(x + (size_t)node * DIM + lg * 32);
#pragma unroll
      for (int q = 0; q < 8; ++q) {
        float4 f = xr[q];
        v[q * 4 + 0] = f.x; v[q * 4 + 1] = f.y; v[q * 4 + 2] = f.z; v[q * 4 + 3] = f.w;
      }
    } else {
#pragma unroll
      for (int q = 0; q < 32; ++q) v[q] = 0.f;
    }
    float sq = 0.f;
#pragma unroll
    for (int q = 0; q < 32; ++q) sq += v[q] * v[q];
    sq += __shfl_xor(sq, 16, 64);
    sq += __shfl_xor(sq, 32, 64);
    float n1 = sqrtf(sq);
    float nc = fmaxf(n1, EPSF);
    float nm = fminf(nc, MAXNORM);
    float scale = 0.5f * logf((1.f + nm) / (1.f - nm)) / nc;
#pragma unroll
    for (int s = 0; s < 4; ++s) {
      unsigned short tmp[8];
#pragma unroll
      for (int e = 0; e < 8; ++e) tmp[e] = f2bf(v[s * 8 + e] * scale);
      int byte = row * 256 + lg * 64 + s * 16;
      byte ^= (row & 7) << 4;
      *(bf16x8*)((char*)At + byte) = *(const bf16x8*)tmp;
    }
  } else {
    // ---- input is bf16 tangent: straight copy into swizzled LDS ----
    const unsigned short* t = (const unsigned short*)xin;
#pragma unroll
    for (int s = 0; s < 4; ++s) {
      bf16x8 frag;
      if (node < N_NODES)
        frag = *(const bf16x8*)(t + (size_t)node * DIM + lg * 32 + s * 8);
      else
        frag = bf16x8{0, 0, 0, 0, 0, 0, 0, 0};
      int byte = row * 256 + lg * 64 + s * 16;
      byte ^= (row & 7) << 4;
      *(bf16x8*)((char*)At + byte) = frag;
    }
  }
  __syncthreads();

  // ---- MFMA: C[16 x 128] per wave ----
  f32x4 acc[8];
#pragma unroll
  for (int n = 0; n < 8; ++n) {
    acc[n][0] = bias[n]; acc[n][1] = bias[n]; acc[n][2] = bias[n]; acc[n][3] = bias[n];
  }
#pragma unroll
  for (int kc = 0; kc < 4; ++kc) {
    int arow = w * 16 + lr;
    int byte = arow * 256 + kc * 64 + lg * 16;
    byte ^= (arow & 7) << 4;
    bf16x8 af = *(const bf16x8*)((const char*)At + byte);
#pragma unroll
    for (int n = 0; n < 8; ++n)
      acc[n] = __builtin_amdgcn_mfma_f32_16x16x32_bf16(af, bf[n][kc], acc[n], 0, 0, 0);
  }

  // ---- expmap0 epilogue: lane holds rows lg*4+j, cols n*16+lr ----
  float rs[4];
#pragma unroll
  for (int j = 0; j < 4; ++j) {
    float s2 = 0.f;
#pragma unroll
    for (int n = 0; n < 8; ++n) s2 += acc[n][j] * acc[n][j];
    s2 += __shfl_xor(s2, 1, 64);
    s2 += __shfl_xor(s2, 2, 64);
    s2 += __shfl_xor(s2, 4, 64);
    s2 += __shfl_xor(s2, 8, 64);
    float n2 = sqrtf(s2);
    float n2c = fmaxf(n2, EPSF);
    rs[j] = tanhf(n2c) / n2c;
  }
#pragma unroll
  for (int j = 0; j < 4; ++j) {
    int nrow = base + w * 16 + lg * 4 + j;
    if (nrow < N_NODES) {
      unsigned short* yr = y + (size_t)nrow * DIM + lr;
#pragma unroll
      for (int n = 0; n < 8; ++n) yr[n * 16] = f2bf(acc[n][j] * rs[j]);
    }
  }
}

// ---------------- classifier head: out = t2 @ Wc^T + bc via MFMA ----------------
// One wave per 16 nodes; K=128 via 4x mfma 16x16x32; N=16 (cols 10..15 unused).
__global__ __launch_bounds__(256) void head_mfma(
    const unsigned short* __restrict__ t2, const float* __restrict__ Wc,
    const float* __restrict__ bc, float* __restrict__ out)
{
  const int base = blockIdx.x * 64;
  const int w = threadIdx.x >> 6;
  const int l = threadIdx.x & 63;
  const int lr = l & 15;
  const int lg = l >> 4;

  // B fragments from Wc (f32 -> bf16 on the fly); rows >= NCLS are zero.
  bf16x8 bw[4];
#pragma unroll
  for (int kc = 0; kc < 4; ++kc) {
    unsigned short tmp[8];
    if (lr < NCLS) {
      const float* wr = Wc + (size_t)lr * DIM + kc * 32 + lg * 8;
#pragma unroll
      for (int e = 0; e < 8; ++e) tmp[e] = f2bf(wr[e]);
    } else {
#pragma unroll
      for (int e = 0; e < 8; ++e) tmp[e] = 0;
    }
    bw[kc] = *(const bf16x8*)tmp;
  }
  const float bias = (lr < NCLS) ? bc[lr] : 0.f;

  const int arow = base + w * 16 + lr;
  f32x4 acc;
  acc[0] = bias; acc[1] = bias; acc[2] = bias; acc[3] = bias;
#pragma unroll
  for (int kc = 0; kc < 4; ++kc) {
    bf16x8 af;
    if (arow < N_NODES)
      af = *(const bf16x8*)(t2 + (size_t)arow * DIM + kc * 32 + lg * 8);
    else
      af = bf16x8{0, 0, 0, 0, 0, 0, 0, 0};
    acc = __builtin_amdgcn_mfma_f32_16x16x32_bf16(af, bw[kc], acc, 0, 0, 0);
  }

  // C layout: col = lr (class), row = lg*4 + j (node within 16)
  if (lr < NCLS) {
#pragma unroll
    for (int j = 0; j < 4; ++j) {
      int nrow = base + w * 16 + lg * 4 + j;
      if (nrow < N_NODES) out[(size_t)nrow * NCLS + lr] = acc[j];
    }
  }
}

extern "C" void kernel_launch(void* const* d_in, const int* in_sizes, int n_in,
                              void* d_out, int out_size, void* d_ws, size_t ws_size,
                              hipStream_t stream)
{
  const int* edge = (const int*)d_in[0];
  const int* src = edge;            // edge_index[0]
  const int* dst = edge + N_EDGES;  // edge_index[1]
  const float* x  = (const float*)d_in[1];
  const float* W1 = (const float*)d_in[2];
  const float* b1 = (const float*)d_in[3];
  const float* W2 = (const float*)d_in[4];
  const float* b2 = (const float*)d_in[5];
  const float* Wc = (const float*)d_in[6];
  const float* bc = (const float*)d_in[7];
  float* out = (float*)d_out;

  unsigned short* ybuf = (unsigned short*)d_ws;          // bf16 y [N, D]
  unsigned short* tbuf = ybuf + (size_t)N_NODES * DIM;   // bf16 tangent [N, D]
  unsigned short* W1b = tbuf + (size_t)N_NODES * DIM;
  unsigned short* W2b = W1b + DIM * DIM;
  int* off  = (int*)(W2b + DIM * DIM);                 // 50001
  int* bsum = off + N_NODES + 4;                       // 64
  int* pos  = bsum + 64;                               // 50000
  int* csr  = pos + N_NODES;                           // 600000

  const int NCHUNK = (N_NODES + 1 + 1023) / 1024;  // 49
  const int NTILE = (N_NODES + 63) / 64;           // 782

  // --- init (zero off) + W->bf16, one kernel ---
  init_kernel<<<(N_NODES + 256) / 256, 256, 0, stream>>>(off, W1, W2, W1b, W2b);

  // --- CSR build (dst identical for both layers; build once) ---
  hist_kernel<<<(N_EDGES + 255) / 256, 256, 0, stream>>>(dst, off);
  scan1_kernel<<<NCHUNK, 1024, 0, stream>>>(off, bsum);
  scan2_kernel<<<1, 64, 0, stream>>>(bsum, NCHUNK);
  scan3_kernel<<<(N_NODES + 256) / 256, 256, 0, stream>>>(off, bsum, pos);
  fill_kernel<<<(N_EDGES + 255) / 256, 256, 0, stream>>>(src, dst, pos, csr);

  // --- Layer 1: x (f32, manifold) -> y1 (bf16) ---
  transform_mfma<0><<<NTILE, 256, 0, stream>>>(x, W1b, b1, ybuf);
  // --- gather + relu + logmap -> t (bf16) ---
  gatherT_kernel<<<(N_NODES + 3) / 4, 256, 0, stream>>>(ybuf, off, csr, tbuf);

  // --- Layer 2: t (bf16 tangent) -> y2 (bf16) ---
  transform_mfma<1><<<NTILE, 256, 0, stream>>>(tbuf, W2b, b2, ybuf);
  // --- gather + relu + logmap -> t2 (bf16) ---
  gatherT_kernel<<<(N_NODES + 3) / 4, 256, 0, stream>>>(ybuf, off, csr, tbuf);

  // --- classifier head ---
  head_mfma<<<NTILE, 256, 0, stream>>>(tbuf, Wc, bc, out);
}

// Round 8
// 178.921 us; speedup vs baseline: 9.7778x; 1.1009x over previous
//
#include <hip/hip_runtime.h>

#define N_NODES 50000
#define N_EDGES 600000
#define DIM 128
#define NCLS 10
#define EPSF 1e-15f
#define MAXNORM 0.99999f  // 1 - 1e-5
#define NTILE ((N_NODES + 63) / 64)   // 782

typedef __attribute__((ext_vector_type(8))) short bf16x8;
typedef __attribute__((ext_vector_type(4))) float f32x4;

__device__ inline float waveSum(float v) {
#pragma unroll
  for (int o = 1; o < 64; o <<= 1) v += __shfl_xor(v, o, 64);
  return v;
}

__device__ inline unsigned short f2bf(float f) {
  union { float f; unsigned u; } c; c.f = f;
  return (unsigned short)((c.u + 0x7FFFu + ((c.u >> 16) & 1u)) >> 16);
}
__device__ inline float bf_lo(unsigned u) {
  union { unsigned u; float f; } c; c.u = u << 16; return c.f;
}
__device__ inline float bf_hi(unsigned u) {
  union { unsigned u; float f; } c; c.u = u & 0xFFFF0000u; return c.f;
}

// ---------------- init: zero CSR offsets + convert W1/W2 to bf16 ----------------
__global__ __launch_bounds__(256) void init_kernel(
    int* __restrict__ off, const float* __restrict__ W1, const float* __restrict__ W2,
    unsigned short* __restrict__ W1b, unsigned short* __restrict__ W2b)
{
  int i = blockIdx.x * 256 + threadIdx.x;
  if (i <= N_NODES) off[i] = 0;
  if (i < DIM * DIM) {
    W1b[i] = f2bf(W1[i]);
    W2b[i] = f2bf(W2[i]);
  }
}

// ---------------- CSR build ----------------

__global__ __launch_bounds__(256) void hist_kernel(
    const int* __restrict__ dst, int* __restrict__ off)
{
  int e = blockIdx.x * 256 + threadIdx.x;
  if (e < N_EDGES) atomicAdd(&off[dst[e] + 1], 1);
}

__global__ __launch_bounds__(1024) void scan1_kernel(
    int* __restrict__ off, int* __restrict__ bsum)
{
  const int gid = blockIdx.x * 1024 + threadIdx.x;
  const int lane = threadIdx.x & 63, wid = threadIdx.x >> 6;
  __shared__ int ws[16];
  int v = (gid <= N_NODES) ? off[gid] : 0;
#pragma unroll
  for (int o = 1; o < 64; o <<= 1) {
    int u = __shfl_up(v, o, 64);
    if (lane >= o) v += u;
  }
  if (lane == 63) ws[wid] = v;
  __syncthreads();
  if (wid == 0) {
    int z = (lane < 16) ? ws[lane] : 0;
#pragma unroll
    for (int o = 1; o < 16; o <<= 1) {
      int u = __shfl_up(z, o, 64);
      if (lane >= o) z += u;
    }
    if (lane < 16) ws[lane] = z;
  }
  __syncthreads();
  if (wid > 0) v += ws[wid - 1];
  if (gid <= N_NODES) off[gid] = v;
  if (threadIdx.x == 1023) bsum[blockIdx.x] = v;
}

// scan3 with scan2 folded in: wave 0 scans the <=64 block sums in-register.
__global__ __launch_bounds__(256) void scan3_kernel(
    int* __restrict__ off, const int* __restrict__ bsum, int* __restrict__ pos,
    int nchunk)
{
  __shared__ int pre[64];
  const int t = threadIdx.x;
  if (t < 64) {
    int v = (t < nchunk) ? bsum[t] : 0;
#pragma unroll
    for (int o = 1; o < 64; o <<= 1) {
      int u = __shfl_up(v, o, 64);
      if (t >= o) v += u;
    }
    pre[t] = v;  // inclusive scan of block sums
  }
  __syncthreads();
  int gid = blockIdx.x * 256 + t;
  if (gid <= N_NODES) {
    int c = gid >> 10;
    int carry = (c == 0) ? 0 : pre[c - 1];
    int v = off[gid] + carry;
    off[gid] = v;
    if (gid < N_NODES) pos[gid] = v;
  }
}

__global__ __launch_bounds__(256) void fill_kernel(
    const int* __restrict__ src, const int* __restrict__ dst,
    int* __restrict__ pos, int* __restrict__ csr_src)
{
  int e = blockIdx.x * 256 + threadIdx.x;
  if (e < N_EDGES) {
    int slot = atomicAdd(&pos[dst[e]], 1);
    csr_src[slot] = src[e];
  }
}

// ---------------- gather + relu + logmap0 -> bf16 tangent ----------------
// One wave per destination node; 64 lanes x 2 bf16 (4B) = 256B row; unroll 8.
__global__ __launch_bounds__(256) void gatherT_kernel(
    const unsigned short* __restrict__ y, const int* __restrict__ off,
    const int* __restrict__ csr_src, unsigned short* __restrict__ tout)
{
  const int node = blockIdx.x * 4 + (threadIdx.x >> 6);
  if (node >= N_NODES) return;
  const int lane = threadIdx.x & 63;
  const int beg = off[node], end = off[node + 1];
  float2 a0 = {0.f, 0.f}, a1 = {0.f, 0.f}, a2 = {0.f, 0.f}, a3 = {0.f, 0.f};
  int j = beg;
  for (; j + 7 < end; j += 8) {
    unsigned u0 = ((const unsigned*)(y + (size_t)csr_src[j    ] * DIM))[lane];
    unsigned u1 = ((const unsigned*)(y + (size_t)csr_src[j + 1] * DIM))[lane];
    unsigned u2 = ((const unsigned*)(y + (size_t)csr_src[j + 2] * DIM))[lane];
    unsigned u3 = ((const unsigned*)(y + (size_t)csr_src[j + 3] * DIM))[lane];
    unsigned u4 = ((const unsigned*)(y + (size_t)csr_src[j + 4] * DIM))[lane];
    unsigned u5 = ((const unsigned*)(y + (size_t)csr_src[j + 5] * DIM))[lane];
    unsigned u6 = ((const unsigned*)(y + (size_t)csr_src[j + 6] * DIM))[lane];
    unsigned u7 = ((const unsigned*)(y + (size_t)csr_src[j + 7] * DIM))[lane];
    a0.x += bf_lo(u0); a0.y += bf_hi(u0);
    a1.x += bf_lo(u1); a1.y += bf_hi(u1);
    a2.x += bf_lo(u2); a2.y += bf_hi(u2);
    a3.x += bf_lo(u3); a3.y += bf_hi(u3);
    a0.x += bf_lo(u4); a0.y += bf_hi(u4);
    a1.x += bf_lo(u5); a1.y += bf_hi(u5);
    a2.x += bf_lo(u6); a2.y += bf_hi(u6);
    a3.x += bf_lo(u7); a3.y += bf_hi(u7);
  }
  for (; j + 3 < end; j += 4) {
    unsigned u0 = ((const unsigned*)(y + (size_t)csr_src[j    ] * DIM))[lane];
    unsigned u1 = ((const unsigned*)(y + (size_t)csr_src[j + 1] * DIM))[lane];
    unsigned u2 = ((const unsigned*)(y + (size_t)csr_src[j + 2] * DIM))[lane];
    unsigned u3 = ((const unsigned*)(y + (size_t)csr_src[j + 3] * DIM))[lane];
    a0.x += bf_lo(u0); a0.y += bf_hi(u0);
    a1.x += bf_lo(u1); a1.y += bf_hi(u1);
    a2.x += bf_lo(u2); a2.y += bf_hi(u2);
    a3.x += bf_lo(u3); a3.y += bf_hi(u3);
  }
  for (; j < end; ++j) {
    unsigned u0 = ((const unsigned*)(y + (size_t)csr_src[j] * DIM))[lane];
    a0.x += bf_lo(u0); a0.y += bf_hi(u0);
  }
  float2 r;
  r.x = fmaxf((a0.x + a1.x) + (a2.x + a3.x), 0.f);  // relu
  r.y = fmaxf((a0.y + a1.y) + (a2.y + a3.y), 0.f);

  // logmap0 across the wave-held 128-dim row
  float s = waveSum(r.x * r.x + r.y * r.y);
  float n = sqrtf(s);
  float nc = fmaxf(n, EPSF);
  float nm = fminf(nc, MAXNORM);
  float scale = 0.5f * logf((1.0f + nm) / (1.0f - nm)) / nc;
  unsigned u = (unsigned)f2bf(r.x * scale) | ((unsigned)f2bf(r.y * scale) << 16);
  ((unsigned*)(tout + (size_t)node * DIM))[lane] = u;
}

// ---------------- fused (logmap0?) -> (W t + b via MFMA) -> expmap0, bf16 out ------
// MODE 0: input f32 on manifold (apply logmap0). MODE 1: input bf16 tangent (direct).
// Persistent blocks grid-stride over 64-node tiles; W^T loaded into per-wave
// registers ONCE per block (32 bf16x8 fragments).
template <int MODE>
__global__ __launch_bounds__(256, 2) void transform_mfma(
    const void* __restrict__ xin, const unsigned short* __restrict__ Wb,
    const float* __restrict__ b, unsigned short* __restrict__ y)
{
  const int tid = threadIdx.x;
  const int w = tid >> 6;
  const int l = tid & 63;
  const int lr = l & 15;   // A-row / B-col within tile
  const int lg = l >> 4;   // k-group 0..3

  __shared__ __align__(16) unsigned short At[64 * DIM];  // swizzled bf16 t-tile

  // B fragments: slot (lg, e) <- W[n*16+lr][kc*32 + lg*8 + e]
  bf16x8 bf[8][4];
#pragma unroll
  for (int n = 0; n < 8; ++n)
#pragma unroll
    for (int kc = 0; kc < 4; ++kc)
      bf[n][kc] = *(const bf16x8*)(Wb + (n * 16 + lr) * DIM + kc * 32 + lg * 8);

  float bias[8];
#pragma unroll
  for (int n = 0; n < 8; ++n) bias[n] = b[n * 16 + lr];

  const int row = w * 16 + lr;

  for (int tile = blockIdx.x; tile < NTILE; tile += gridDim.x) {
    const int base = tile * 64;
    const int node = base + row;
    __syncthreads();  // At from previous tile fully consumed

    if (MODE == 0) {
      // ---- logmap0: lane handles row lr, cols lg*32..+31 ----
      const float* x = (const float*)xin;
      float v[32];
      if (node < N_NODES) {
        const float4* xr = (const float4*)(x + (size_t)node * DIM + lg * 32);
#pragma unroll
        for (int q = 0; q < 8; ++q) {
          float4 f = xr[q];
          v[q * 4 + 0] = f.x; v[q * 4 + 1] = f.y; v[q * 4 + 2] = f.z; v[q * 4 + 3] = f.w;
        }
      } else {
#pragma unroll
        for (int q = 0; q < 32; ++q) v[q] = 0.f;
      }
      float sq = 0.f;
#pragma unroll
      for (int q = 0; q < 32; ++q) sq += v[q] * v[q];
      sq += __shfl_xor(sq, 16, 64);
      sq += __shfl_xor(sq, 32, 64);
      float n1 = sqrtf(sq);
      float nc = fmaxf(n1, EPSF);
      float nm = fminf(nc, MAXNORM);
      float scale = 0.5f * logf((1.f + nm) / (1.f - nm)) / nc;
#pragma unroll
      for (int s = 0; s < 4; ++s) {
        unsigned short tmp[8];
#pragma unroll
        for (int e = 0; e < 8; ++e) tmp[e] = f2bf(v[s * 8 + e] * scale);
        int byte = row * 256 + lg * 64 + s * 16;
        byte ^= (row & 7) << 4;
        *(bf16x8*)((char*)At + byte) = *(const bf16x8*)tmp;
      }
    } else {
      // ---- input is bf16 tangent: straight copy into swizzled LDS ----
      const unsigned short* t = (const unsigned short*)xin;
#pragma unroll
      for (int s = 0; s < 4; ++s) {
        bf16x8 frag;
        if (node < N_NODES)
          frag = *(const bf16x8*)(t + (size_t)node * DIM + lg * 32 + s * 8);
        else
          frag = bf16x8{0, 0, 0, 0, 0, 0, 0, 0};
        int byte = row * 256 + lg * 64 + s * 16;
        byte ^= (row & 7) << 4;
        *(bf16x8*)((char*)At + byte) = frag;
      }
    }
    __syncthreads();

    // ---- MFMA: C[16 x 128] per wave ----
    f32x4 acc[8];
#pragma unroll
    for (int n = 0; n < 8; ++n) {
      acc[n][0] = bias[n]; acc[n][1] = bias[n]; acc[n][2] = bias[n]; acc[n][3] = bias[n];
    }
#pragma unroll
    for (int kc = 0; kc < 4; ++kc) {
      int arow = w * 16 + lr;
      int byte = arow * 256 + kc * 64 + lg * 16;
      byte ^= (arow & 7) << 4;
      bf16x8 af = *(const bf16x8*)((const char*)At + byte);
#pragma unroll
      for (int n = 0; n < 8; ++n)
        acc[n] = __builtin_amdgcn_mfma_f32_16x16x32_bf16(af, bf[n][kc], acc[n], 0, 0, 0);
    }

    // ---- expmap0 epilogue: lane holds rows lg*4+j, cols n*16+lr ----
    float rs[4];
#pragma unroll
    for (int j = 0; j < 4; ++j) {
      float s2 = 0.f;
#pragma unroll
      for (int n = 0; n < 8; ++n) s2 += acc[n][j] * acc[n][j];
      s2 += __shfl_xor(s2, 1, 64);
      s2 += __shfl_xor(s2, 2, 64);
      s2 += __shfl_xor(s2, 4, 64);
      s2 += __shfl_xor(s2, 8, 64);
      float n2 = sqrtf(s2);
      float n2c = fmaxf(n2, EPSF);
      rs[j] = tanhf(n2c) / n2c;
    }
#pragma unroll
    for (int j = 0; j < 4; ++j) {
      int nrow = base + w * 16 + lg * 4 + j;
      if (nrow < N_NODES) {
        unsigned short* yr = y + (size_t)nrow * DIM + lr;
#pragma unroll
        for (int n = 0; n < 8; ++n) yr[n * 16] = f2bf(acc[n][j] * rs[j]);
      }
    }
  }
}

// ---------------- classifier head: out = t2 @ Wc^T + bc via MFMA ----------------
__global__ __launch_bounds__(256) void head_mfma(
    const unsigned short* __restrict__ t2, const float* __restrict__ Wc,
    const float* __restrict__ bc, float* __restrict__ out)
{
  const int base = blockIdx.x * 64;
  const int w = threadIdx.x >> 6;
  const int l = threadIdx.x & 63;
  const int lr = l & 15;
  const int lg = l >> 4;

  bf16x8 bw[4];
#pragma unroll
  for (int kc = 0; kc < 4; ++kc) {
    unsigned short tmp[8];
    if (lr < NCLS) {
      const float* wr = Wc + (size_t)lr * DIM + kc * 32 + lg * 8;
#pragma unroll
      for (int e = 0; e < 8; ++e) tmp[e] = f2bf(wr[e]);
    } else {
#pragma unroll
      for (int e = 0; e < 8; ++e) tmp[e] = 0;
    }
    bw[kc] = *(const bf16x8*)tmp;
  }
  const float bias = (lr < NCLS) ? bc[lr] : 0.f;

  const int arow = base + w * 16 + lr;
  f32x4 acc;
  acc[0] = bias; acc[1] = bias; acc[2] = bias; acc[3] = bias;
#pragma unroll
  for (int kc = 0; kc < 4; ++kc) {
    bf16x8 af;
    if (arow < N_NODES)
      af = *(const bf16x8*)(t2 + (size_t)arow * DIM + kc * 32 + lg * 8);
    else
      af = bf16x8{0, 0, 0, 0, 0, 0, 0, 0};
    acc = __builtin_amdgcn_mfma_f32_16x16x32_bf16(af, bw[kc], acc, 0, 0, 0);
  }

  if (lr < NCLS) {
#pragma unroll
    for (int j = 0; j < 4; ++j) {
      int nrow = base + w * 16 + lg * 4 + j;
      if (nrow < N_NODES) out[(size_t)nrow * NCLS + lr] = acc[j];
    }
  }
}

extern "C" void kernel_launch(void* const* d_in, const int* in_sizes, int n_in,
                              void* d_out, int out_size, void* d_ws, size_t ws_size,
                              hipStream_t stream)
{
  const int* edge = (const int*)d_in[0];
  const int* src = edge;            // edge_index[0]
  const int* dst = edge + N_EDGES;  // edge_index[1]
  const float* x  = (const float*)d_in[1];
  const float* W1 = (const float*)d_in[2];
  const float* b1 = (const float*)d_in[3];
  const float* W2 = (const float*)d_in[4];
  const float* b2 = (const float*)d_in[5];
  const float* Wc = (const float*)d_in[6];
  const float* bc = (const float*)d_in[7];
  float* out = (float*)d_out;

  unsigned short* ybuf = (unsigned short*)d_ws;          // bf16 y [N, D]
  unsigned short* tbuf = ybuf + (size_t)N_NODES * DIM;   // bf16 tangent [N, D]
  unsigned short* W1b = tbuf + (size_t)N_NODES * DIM;
  unsigned short* W2b = W1b + DIM * DIM;
  int* off  = (int*)(W2b + DIM * DIM);                 // 50001
  int* bsum = off + N_NODES + 4;                       // 64
  int* pos  = bsum + 64;                               // 50000
  int* csr  = pos + N_NODES;                           // 600000

  const int NCHUNK = (N_NODES + 1 + 1023) / 1024;  // 49

  // --- init (zero off) + W->bf16 ---
  init_kernel<<<(N_NODES + 256) / 256, 256, 0, stream>>>(off, W1, W2, W1b, W2b);

  // --- CSR build (dst identical for both layers; build once) ---
  hist_kernel<<<(N_EDGES + 255) / 256, 256, 0, stream>>>(dst, off);
  scan1_kernel<<<NCHUNK, 1024, 0, stream>>>(off, bsum);
  scan3_kernel<<<(N_NODES + 256) / 256, 256, 0, stream>>>(off, bsum, pos, NCHUNK);
  fill_kernel<<<(N_EDGES + 255) / 256, 256, 0, stream>>>(src, dst, pos, csr);

  // --- Layer 1: x (f32, manifold) -> y1 (bf16) ---
  transform_mfma<0><<<512, 256, 0, stream>>>(x, W1b, b1, ybuf);
  // --- gather + relu + logmap -> t (bf16) ---
  gatherT_kernel<<<(N_NODES + 3) / 4, 256, 0, stream>>>(ybuf, off, csr, tbuf);

  // --- Layer 2: t (bf16 tangent) -> y2 (bf16) ---
  transform_mfma<1><<<512, 256, 0, stream>>>(tbuf, W2b, b2, ybuf);
  // --- gather + relu + logmap -> t2 (bf16) ---
  gatherT_kernel<<<(N_NODES + 3) / 4, 256, 0, stream>>>(ybuf, off, csr, tbuf);

  // --- classifier head ---
  head_mfma<<<NTILE, 256, 0, stream>>>(tbuf, Wc, bc, out);
}

// Round 9
// 151.841 us; speedup vs baseline: 11.5216x; 1.1783x over previous
//
#include <hip/hip_runtime.h>

#define N_NODES 50000
#define N_EDGES 600000
#define DIM 128
#define NCLS 10
#define ELLW 64                      // max supported degree (mean is 12; P(>64) ~ 1e-33)
#define EPSF 1e-15f
#define MAXNORM 0.99999f  // 1 - 1e-5
#define NTILE ((N_NODES + 63) / 64)   // 782

typedef __attribute__((ext_vector_type(8))) short bf16x8;
typedef __attribute__((ext_vector_type(4))) float f32x4;

__device__ inline float waveSum(float v) {
#pragma unroll
  for (int o = 1; o < 64; o <<= 1) v += __shfl_xor(v, o, 64);
  return v;
}

__device__ inline unsigned short f2bf(float f) {
  union { float f; unsigned u; } c; c.f = f;
  return (unsigned short)((c.u + 0x7FFFu + ((c.u >> 16) & 1u)) >> 16);
}
__device__ inline float bf_lo(unsigned u) {
  union { unsigned u; float f; } c; c.u = u << 16; return c.f;
}
__device__ inline float bf_hi(unsigned u) {
  union { unsigned u; float f; } c; c.u = u & 0xFFFF0000u; return c.f;
}

// ---------------- init: zero ELL cursors + convert W1/W2 to bf16 ----------------
__global__ __launch_bounds__(256) void init_kernel(
    int* __restrict__ cursor, const float* __restrict__ W1, const float* __restrict__ W2,
    unsigned short* __restrict__ W1b, unsigned short* __restrict__ W2b)
{
  int i = blockIdx.x * 256 + threadIdx.x;
  if (i < N_NODES) cursor[i] = 0;
  if (i < DIM * DIM) {
    W1b[i] = f2bf(W1[i]);
    W2b[i] = f2bf(W2[i]);
  }
}

// ---------------- ELL build: one atomic scatter, no scan ----------------
__global__ __launch_bounds__(256) void fill_kernel(
    const int* __restrict__ src, const int* __restrict__ dst,
    int* __restrict__ cursor, int* __restrict__ ell)
{
  int e = blockIdx.x * 256 + threadIdx.x;
  if (e < N_EDGES) {
    int d = dst[e];
    int slot = atomicAdd(&cursor[d], 1);
    ell[d * ELLW + slot] = src[e];
  }
}

// ---------------- gather + relu + logmap0 -> bf16 tangent ----------------
// One wave per destination node; 64 lanes x 2 bf16 (4B) = 256B row; unroll 8.
__global__ __launch_bounds__(256) void gatherT_kernel(
    const unsigned short* __restrict__ y, const int* __restrict__ cursor,
    const int* __restrict__ ell, unsigned short* __restrict__ tout)
{
  const int node = blockIdx.x * 4 + (threadIdx.x >> 6);
  if (node >= N_NODES) return;
  const int lane = threadIdx.x & 63;
  const int* lst = ell + node * ELLW;
  const int cnt = cursor[node];
  float2 a0 = {0.f, 0.f}, a1 = {0.f, 0.f}, a2 = {0.f, 0.f}, a3 = {0.f, 0.f};
  int j = 0;
  for (; j + 7 < cnt; j += 8) {
    unsigned u0 = ((const unsigned*)(y + (size_t)lst[j    ] * DIM))[lane];
    unsigned u1 = ((const unsigned*)(y + (size_t)lst[j + 1] * DIM))[lane];
    unsigned u2 = ((const unsigned*)(y + (size_t)lst[j + 2] * DIM))[lane];
    unsigned u3 = ((const unsigned*)(y + (size_t)lst[j + 3] * DIM))[lane];
    unsigned u4 = ((const unsigned*)(y + (size_t)lst[j + 4] * DIM))[lane];
    unsigned u5 = ((const unsigned*)(y + (size_t)lst[j + 5] * DIM))[lane];
    unsigned u6 = ((const unsigned*)(y + (size_t)lst[j + 6] * DIM))[lane];
    unsigned u7 = ((const unsigned*)(y + (size_t)lst[j + 7] * DIM))[lane];
    a0.x += bf_lo(u0); a0.y += bf_hi(u0);
    a1.x += bf_lo(u1); a1.y += bf_hi(u1);
    a2.x += bf_lo(u2); a2.y += bf_hi(u2);
    a3.x += bf_lo(u3); a3.y += bf_hi(u3);
    a0.x += bf_lo(u4); a0.y += bf_hi(u4);
    a1.x += bf_lo(u5); a1.y += bf_hi(u5);
    a2.x += bf_lo(u6); a2.y += bf_hi(u6);
    a3.x += bf_lo(u7); a3.y += bf_hi(u7);
  }
  for (; j + 3 < cnt; j += 4) {
    unsigned u0 = ((const unsigned*)(y + (size_t)lst[j    ] * DIM))[lane];
    unsigned u1 = ((const unsigned*)(y + (size_t)lst[j + 1] * DIM))[lane];
    unsigned u2 = ((const unsigned*)(y + (size_t)lst[j + 2] * DIM))[lane];
    unsigned u3 = ((const unsigned*)(y + (size_t)lst[j + 3] * DIM))[lane];
    a0.x += bf_lo(u0); a0.y += bf_hi(u0);
    a1.x += bf_lo(u1); a1.y += bf_hi(u1);
    a2.x += bf_lo(u2); a2.y += bf_hi(u2);
    a3.x += bf_lo(u3); a3.y += bf_hi(u3);
  }
  for (; j < cnt; ++j) {
    unsigned u0 = ((const unsigned*)(y + (size_t)lst[j] * DIM))[lane];
    a0.x += bf_lo(u0); a0.y += bf_hi(u0);
  }
  float2 r;
  r.x = fmaxf((a0.x + a1.x) + (a2.x + a3.x), 0.f);  // relu
  r.y = fmaxf((a0.y + a1.y) + (a2.y + a3.y), 0.f);

  // logmap0 across the wave-held 128-dim row
  float s = waveSum(r.x * r.x + r.y * r.y);
  float n = sqrtf(s);
  float nc = fmaxf(n, EPSF);
  float nm = fminf(nc, MAXNORM);
  float scale = 0.5f * logf((1.0f + nm) / (1.0f - nm)) / nc;
  unsigned u = (unsigned)f2bf(r.x * scale) | ((unsigned)f2bf(r.y * scale) << 16);
  ((unsigned*)(tout + (size_t)node * DIM))[lane] = u;
}

// ---------------- fused (logmap0?) -> (W t + b via MFMA) -> expmap0, bf16 out ------
// MODE 0: input f32 on manifold (apply logmap0). MODE 1: input bf16 tangent (direct).
// Persistent blocks grid-stride over 64-node tiles; W^T loaded into per-wave
// registers ONCE per block (32 bf16x8 fragments).
template <int MODE>
__global__ __launch_bounds__(256, 2) void transform_mfma(
    const void* __restrict__ xin, const unsigned short* __restrict__ Wb,
    const float* __restrict__ b, unsigned short* __restrict__ y)
{
  const int tid = threadIdx.x;
  const int w = tid >> 6;
  const int l = tid & 63;
  const int lr = l & 15;   // A-row / B-col within tile
  const int lg = l >> 4;   // k-group 0..3

  __shared__ __align__(16) unsigned short At[64 * DIM];  // swizzled bf16 t-tile

  // B fragments: slot (lg, e) <- W[n*16+lr][kc*32 + lg*8 + e]
  bf16x8 bf[8][4];
#pragma unroll
  for (int n = 0; n < 8; ++n)
#pragma unroll
    for (int kc = 0; kc < 4; ++kc)
      bf[n][kc] = *(const bf16x8*)(Wb + (n * 16 + lr) * DIM + kc * 32 + lg * 8);

  float bias[8];
#pragma unroll
  for (int n = 0; n < 8; ++n) bias[n] = b[n * 16 + lr];

  const int row = w * 16 + lr;

  for (int tile = blockIdx.x; tile < NTILE; tile += gridDim.x) {
    const int base = tile * 64;
    const int node = base + row;
    __syncthreads();  // At from previous tile fully consumed

    if (MODE == 0) {
      // ---- logmap0: lane handles row lr, cols lg*32..+31 ----
      const float* x = (const float*)xin;
      float v[32];
      if (node < N_NODES) {
        const float4* xr = (const float4*)(x + (size_t)node * DIM + lg * 32);
#pragma unroll
        for (int q = 0; q < 8; ++q) {
          float4 f = xr[q];
          v[q * 4 + 0] = f.x; v[q * 4 + 1] = f.y; v[q * 4 + 2] = f.z; v[q * 4 + 3] = f.w;
        }
      } else {
#pragma unroll
        for (int q = 0; q < 32; ++q) v[q] = 0.f;
      }
      float sq = 0.f;
#pragma unroll
      for (int q = 0; q < 32; ++q) sq += v[q] * v[q];
      sq += __shfl_xor(sq, 16, 64);
      sq += __shfl_xor(sq, 32, 64);
      float n1 = sqrtf(sq);
      float nc = fmaxf(n1, EPSF);
      float nm = fminf(nc, MAXNORM);
      float scale = 0.5f * logf((1.f + nm) / (1.f - nm)) / nc;
#pragma unroll
      for (int s = 0; s < 4; ++s) {
        unsigned short tmp[8];
#pragma unroll
        for (int e = 0; e < 8; ++e) tmp[e] = f2bf(v[s * 8 + e] * scale);
        int byte = row * 256 + lg * 64 + s * 16;
        byte ^= (row & 7) << 4;
        *(bf16x8*)((char*)At + byte) = *(const bf16x8*)tmp;
      }
    } else {
      // ---- input is bf16 tangent: straight copy into swizzled LDS ----
      const unsigned short* t = (const unsigned short*)xin;
#pragma unroll
      for (int s = 0; s < 4; ++s) {
        bf16x8 frag;
        if (node < N_NODES)
          frag = *(const bf16x8*)(t + (size_t)node * DIM + lg * 32 + s * 8);
        else
          frag = bf16x8{0, 0, 0, 0, 0, 0, 0, 0};
        int byte = row * 256 + lg * 64 + s * 16;
        byte ^= (row & 7) << 4;
        *(bf16x8*)((char*)At + byte) = frag;
      }
    }
    __syncthreads();

    // ---- MFMA: C[16 x 128] per wave ----
    f32x4 acc[8];
#pragma unroll
    for (int n = 0; n < 8; ++n) {
      acc[n][0] = bias[n]; acc[n][1] = bias[n]; acc[n][2] = bias[n]; acc[n][3] = bias[n];
    }
#pragma unroll
    for (int kc = 0; kc < 4; ++kc) {
      int arow = w * 16 + lr;
      int byte = arow * 256 + kc * 64 + lg * 16;
      byte ^= (arow & 7) << 4;
      bf16x8 af = *(const bf16x8*)((const char*)At + byte);
#pragma unroll
      for (int n = 0; n < 8; ++n)
        acc[n] = __builtin_amdgcn_mfma_f32_16x16x32_bf16(af, bf[n][kc], acc[n], 0, 0, 0);
    }

    // ---- expmap0 epilogue: lane holds rows lg*4+j, cols n*16+lr ----
    float rs[4];
#pragma unroll
    for (int j = 0; j < 4; ++j) {
      float s2 = 0.f;
#pragma unroll
      for (int n = 0; n < 8; ++n) s2 += acc[n][j] * acc[n][j];
      s2 += __shfl_xor(s2, 1, 64);
      s2 += __shfl_xor(s2, 2, 64);
      s2 += __shfl_xor(s2, 4, 64);
      s2 += __shfl_xor(s2, 8, 64);
      float n2 = sqrtf(s2);
      float n2c = fmaxf(n2, EPSF);
      rs[j] = tanhf(n2c) / n2c;
    }
#pragma unroll
    for (int j = 0; j < 4; ++j) {
      int nrow = base + w * 16 + lg * 4 + j;
      if (nrow < N_NODES) {
        unsigned short* yr = y + (size_t)nrow * DIM + lr;
#pragma unroll
        for (int n = 0; n < 8; ++n) yr[n * 16] = f2bf(acc[n][j] * rs[j]);
      }
    }
  }
}

// ---------------- classifier head: out = t2 @ Wc^T + bc via MFMA ----------------
__global__ __launch_bounds__(256) void head_mfma(
    const unsigned short* __restrict__ t2, const float* __restrict__ Wc,
    const float* __restrict__ bc, float* __restrict__ out)
{
  const int base = blockIdx.x * 64;
  const int w = threadIdx.x >> 6;
  const int l = threadIdx.x & 63;
  const int lr = l & 15;
  const int lg = l >> 4;

  bf16x8 bw[4];
#pragma unroll
  for (int kc = 0; kc < 4; ++kc) {
    unsigned short tmp[8];
    if (lr < NCLS) {
      const float* wr = Wc + (size_t)lr * DIM + kc * 32 + lg * 8;
#pragma unroll
      for (int e = 0; e < 8; ++e) tmp[e] = f2bf(wr[e]);
    } else {
#pragma unroll
      for (int e = 0; e < 8; ++e) tmp[e] = 0;
    }
    bw[kc] = *(const bf16x8*)tmp;
  }
  const float bias = (lr < NCLS) ? bc[lr] : 0.f;

  const int arow = base + w * 16 + lr;
  f32x4 acc;
  acc[0] = bias; acc[1] = bias; acc[2] = bias; acc[3] = bias;
#pragma unroll
  for (int kc = 0; kc < 4; ++kc) {
    bf16x8 af;
    if (arow < N_NODES)
      af = *(const bf16x8*)(t2 + (size_t)arow * DIM + kc * 32 + lg * 8);
    else
      af = bf16x8{0, 0, 0, 0, 0, 0, 0, 0};
    acc = __builtin_amdgcn_mfma_f32_16x16x32_bf16(af, bw[kc], acc, 0, 0, 0);
  }

  if (lr < NCLS) {
#pragma unroll
    for (int j = 0; j < 4; ++j) {
      int nrow = base + w * 16 + lg * 4 + j;
      if (nrow < N_NODES) out[(size_t)nrow * NCLS + lr] = acc[j];
    }
  }
}

extern "C" void kernel_launch(void* const* d_in, const int* in_sizes, int n_in,
                              void* d_out, int out_size, void* d_ws, size_t ws_size,
                              hipStream_t stream)
{
  const int* edge = (const int*)d_in[0];
  const int* src = edge;            // edge_index[0]
  const int* dst = edge + N_EDGES;  // edge_index[1]
  const float* x  = (const float*)d_in[1];
  const float* W1 = (const float*)d_in[2];
  const float* b1 = (const float*)d_in[3];
  const float* W2 = (const float*)d_in[4];
  const float* b2 = (const float*)d_in[5];
  const float* Wc = (const float*)d_in[6];
  const float* bc = (const float*)d_in[7];
  float* out = (float*)d_out;

  unsigned short* ybuf = (unsigned short*)d_ws;          // bf16 y [N, D]
  unsigned short* tbuf = ybuf + (size_t)N_NODES * DIM;   // bf16 tangent [N, D]
  unsigned short* W1b = tbuf + (size_t)N_NODES * DIM;
  unsigned short* W2b = W1b + DIM * DIM;
  int* cursor = (int*)(W2b + DIM * DIM);               // 50000 (degree counts)
  int* ell    = cursor + N_NODES;                      // 50000 * ELLW

  // --- init (zero cursors) + W->bf16 ---
  init_kernel<<<(N_NODES + 255) / 256, 256, 0, stream>>>(cursor, W1, W2, W1b, W2b);

  // --- ELL build: single atomic scatter (replaces hist+scan+fill) ---
  fill_kernel<<<(N_EDGES + 255) / 256, 256, 0, stream>>>(src, dst, cursor, ell);

  // --- Layer 1: x (f32, manifold) -> y1 (bf16) ---
  transform_mfma<0><<<512, 256, 0, stream>>>(x, W1b, b1, ybuf);
  // --- gather + relu + logmap -> t (bf16) ---
  gatherT_kernel<<<(N_NODES + 3) / 4, 256, 0, stream>>>(ybuf, cursor, ell, tbuf);

  // --- Layer 2: t (bf16 tangent) -> y2 (bf16) ---
  transform_mfma<1><<<512, 256, 0, stream>>>(tbuf, W2b, b2, ybuf);
  // --- gather + relu + logmap -> t2 (bf16) ---
  gatherT_kernel<<<(N_NODES + 3) / 4, 256, 0, stream>>>(ybuf, cursor, ell, tbuf);

  // --- classifier head ---
  head_mfma<<<NTILE, 256, 0, stream>>>(tbuf, Wc, bc, out);
}

// Round 10
// 135.865 us; speedup vs baseline: 12.8764x; 1.1176x over previous
//
#include <hip/hip_runtime.h>

#define N_NODES 50000
#define N_EDGES 600000
#define DIM 128
#define NCLS 10
#define ELLW 64                      // max supported degree (mean 12; P(>64) ~ 1e-33)
#define CURSTRIDE 16                 // one cursor per 64B line (atomic de-serialization)
#define EPSF 1e-15f
#define MAXNORM 0.99999f  // 1 - 1e-5
#define NTILE ((N_NODES + 63) / 64)   // 782
#define FILL_BLOCKS 586               // ceil(600000 / (256*4))
#define XFORM_BLOCKS 512

typedef __attribute__((ext_vector_type(8))) short bf16x8;
typedef __attribute__((ext_vector_type(4))) float f32x4;

__device__ inline float waveSum(float v) {
#pragma unroll
  for (int o = 1; o < 64; o <<= 1) v += __shfl_xor(v, o, 64);
  return v;
}

__device__ inline unsigned short f2bf(float f) {
  union { float f; unsigned u; } c; c.f = f;
  return (unsigned short)((c.u + 0x7FFFu + ((c.u >> 16) & 1u)) >> 16);
}
__device__ inline float bf_lo(unsigned u) {
  union { unsigned u; float f; } c; c.u = u << 16; return c.f;
}
__device__ inline float bf_hi(unsigned u) {
  union { unsigned u; float f; } c; c.u = u & 0xFFFF0000u; return c.f;
}

// ---------------- init: zero padded ELL cursors + convert W1/W2 to bf16 ----------------
__global__ __launch_bounds__(256) void init_kernel(
    int* __restrict__ cursor, const float* __restrict__ W1, const float* __restrict__ W2,
    unsigned short* __restrict__ W1b, unsigned short* __restrict__ W2b)
{
  int i = blockIdx.x * 256 + threadIdx.x;
  if (i < N_NODES) cursor[i * CURSTRIDE] = 0;
  if (i < DIM * DIM) {
    W1b[i] = f2bf(W1[i]);
    W2b[i] = f2bf(W2[i]);
  }
}

// ---------------- fused: ELL build (blocks < FILL_BLOCKS) + layer-1 transform ------
// Fill: 4 edges/thread, unrolled independent atomic chains, line-padded cursors.
// Transform (MODE 0 semantics): logmap0 -> W1*t+b1 (MFMA) -> expmap0 -> bf16 y.
__global__ __launch_bounds__(256, 2) void fill_transform(
    const int* __restrict__ src, const int* __restrict__ dst,
    int* __restrict__ cursor, int* __restrict__ ell,
    const float* __restrict__ x, const unsigned short* __restrict__ Wb,
    const float* __restrict__ b, unsigned short* __restrict__ y)
{
  __shared__ __align__(16) unsigned short At[64 * DIM];  // swizzled bf16 t-tile

  if (blockIdx.x < FILL_BLOCKS) {
    const int nthr = FILL_BLOCKS * 256;
    const int e = blockIdx.x * 256 + threadIdx.x;
    const int e0 = e, e1 = e + nthr, e2 = e + 2 * nthr, e3 = e + 3 * nthr;
    int d0, d1, d2, d3, s0, s1, s2, s3;
    // issue all loads first
    if (e0 < N_EDGES) { d0 = dst[e0]; s0 = src[e0]; }
    if (e1 < N_EDGES) { d1 = dst[e1]; s1 = src[e1]; }
    if (e2 < N_EDGES) { d2 = dst[e2]; s2 = src[e2]; }
    if (e3 < N_EDGES) { d3 = dst[e3]; s3 = src[e3]; }
    int p0, p1, p2, p3;
    if (e0 < N_EDGES) p0 = atomicAdd(&cursor[d0 * CURSTRIDE], 1);
    if (e1 < N_EDGES) p1 = atomicAdd(&cursor[d1 * CURSTRIDE], 1);
    if (e2 < N_EDGES) p2 = atomicAdd(&cursor[d2 * CURSTRIDE], 1);
    if (e3 < N_EDGES) p3 = atomicAdd(&cursor[d3 * CURSTRIDE], 1);
    if (e0 < N_EDGES) ell[d0 * ELLW + p0] = s0;
    if (e1 < N_EDGES) ell[d1 * ELLW + p1] = s1;
    if (e2 < N_EDGES) ell[d2 * ELLW + p2] = s2;
    if (e3 < N_EDGES) ell[d3 * ELLW + p3] = s3;
    return;
  }

  // ---------------- transform path ----------------
  const int tid = threadIdx.x;
  const int w = tid >> 6;
  const int l = tid & 63;
  const int lr = l & 15;   // A-row / B-col within tile
  const int lg = l >> 4;   // k-group 0..3

  bf16x8 bf[8][4];
#pragma unroll
  for (int n = 0; n < 8; ++n)
#pragma unroll
    for (int kc = 0; kc < 4; ++kc)
      bf[n][kc] = *(const bf16x8*)(Wb + (n * 16 + lr) * DIM + kc * 32 + lg * 8);

  float bias[8];
#pragma unroll
  for (int n = 0; n < 8; ++n) bias[n] = b[n * 16 + lr];

  const int row = w * 16 + lr;

  for (int tile = blockIdx.x - FILL_BLOCKS; tile < NTILE; tile += XFORM_BLOCKS) {
    const int base = tile * 64;
    const int node = base + row;
    __syncthreads();  // At from previous tile fully consumed

    float v[32];
    if (node < N_NODES) {
      const float4* xr = (const float4*)(x + (size_t)node * DIM + lg * 32);
#pragma unroll
      for (int q = 0; q < 8; ++q) {
        float4 f = xr[q];
        v[q * 4 + 0] = f.x; v[q * 4 + 1] = f.y; v[q * 4 + 2] = f.z; v[q * 4 + 3] = f.w;
      }
    } else {
#pragma unroll
      for (int q = 0; q < 32; ++q) v[q] = 0.f;
    }
    float sq = 0.f;
#pragma unroll
    for (int q = 0; q < 32; ++q) sq += v[q] * v[q];
    sq += __shfl_xor(sq, 16, 64);
    sq += __shfl_xor(sq, 32, 64);
    float n1 = sqrtf(sq);
    float nc = fmaxf(n1, EPSF);
    float nm = fminf(nc, MAXNORM);
    float scale = 0.5f * logf((1.f + nm) / (1.f - nm)) / nc;
#pragma unroll
    for (int s = 0; s < 4; ++s) {
      unsigned short tmp[8];
#pragma unroll
      for (int e = 0; e < 8; ++e) tmp[e] = f2bf(v[s * 8 + e] * scale);
      int byte = row * 256 + lg * 64 + s * 16;
      byte ^= (row & 7) << 4;
      *(bf16x8*)((char*)At + byte) = *(const bf16x8*)tmp;
    }
    __syncthreads();

    f32x4 acc[8];
#pragma unroll
    for (int n = 0; n < 8; ++n) {
      acc[n][0] = bias[n]; acc[n][1] = bias[n]; acc[n][2] = bias[n]; acc[n][3] = bias[n];
    }
#pragma unroll
    for (int kc = 0; kc < 4; ++kc) {
      int arow = w * 16 + lr;
      int byte = arow * 256 + kc * 64 + lg * 16;
      byte ^= (arow & 7) << 4;
      bf16x8 af = *(const bf16x8*)((const char*)At + byte);
#pragma unroll
      for (int n = 0; n < 8; ++n)
        acc[n] = __builtin_amdgcn_mfma_f32_16x16x32_bf16(af, bf[n][kc], acc[n], 0, 0, 0);
    }

    float rs[4];
#pragma unroll
    for (int j = 0; j < 4; ++j) {
      float s2 = 0.f;
#pragma unroll
      for (int n = 0; n < 8; ++n) s2 += acc[n][j] * acc[n][j];
      s2 += __shfl_xor(s2, 1, 64);
      s2 += __shfl_xor(s2, 2, 64);
      s2 += __shfl_xor(s2, 4, 64);
      s2 += __shfl_xor(s2, 8, 64);
      float n2 = sqrtf(s2);
      float n2c = fmaxf(n2, EPSF);
      rs[j] = tanhf(n2c) / n2c;
    }
#pragma unroll
    for (int j = 0; j < 4; ++j) {
      int nrow = base + w * 16 + lg * 4 + j;
      if (nrow < N_NODES) {
        unsigned short* yr = y + (size_t)nrow * DIM + lr;
#pragma unroll
        for (int n = 0; n < 8; ++n) yr[n * 16] = f2bf(acc[n][j] * rs[j]);
      }
    }
  }
}

// ---------------- gather + relu + logmap0 -> bf16 tangent ----------------
__global__ __launch_bounds__(256) void gatherT_kernel(
    const unsigned short* __restrict__ y, const int* __restrict__ cursor,
    const int* __restrict__ ell, unsigned short* __restrict__ tout)
{
  const int node = blockIdx.x * 4 + (threadIdx.x >> 6);
  if (node >= N_NODES) return;
  const int lane = threadIdx.x & 63;
  const int* lst = ell + node * ELLW;
  const int cnt = cursor[node * CURSTRIDE];
  float2 a0 = {0.f, 0.f}, a1 = {0.f, 0.f}, a2 = {0.f, 0.f}, a3 = {0.f, 0.f};
  int j = 0;
  for (; j + 7 < cnt; j += 8) {
    unsigned u0 = ((const unsigned*)(y + (size_t)lst[j    ] * DIM))[lane];
    unsigned u1 = ((const unsigned*)(y + (size_t)lst[j + 1] * DIM))[lane];
    unsigned u2 = ((const unsigned*)(y + (size_t)lst[j + 2] * DIM))[lane];
    unsigned u3 = ((const unsigned*)(y + (size_t)lst[j + 3] * DIM))[lane];
    unsigned u4 = ((const unsigned*)(y + (size_t)lst[j + 4] * DIM))[lane];
    unsigned u5 = ((const unsigned*)(y + (size_t)lst[j + 5] * DIM))[lane];
    unsigned u6 = ((const unsigned*)(y + (size_t)lst[j + 6] * DIM))[lane];
    unsigned u7 = ((const unsigned*)(y + (size_t)lst[j + 7] * DIM))[lane];
    a0.x += bf_lo(u0); a0.y += bf_hi(u0);
    a1.x += bf_lo(u1); a1.y += bf_hi(u1);
    a2.x += bf_lo(u2); a2.y += bf_hi(u2);
    a3.x += bf_lo(u3); a3.y += bf_hi(u3);
    a0.x += bf_lo(u4); a0.y += bf_hi(u4);
    a1.x += bf_lo(u5); a1.y += bf_hi(u5);
    a2.x += bf_lo(u6); a2.y += bf_hi(u6);
    a3.x += bf_lo(u7); a3.y += bf_hi(u7);
  }
  for (; j + 3 < cnt; j += 4) {
    unsigned u0 = ((const unsigned*)(y + (size_t)lst[j    ] * DIM))[lane];
    unsigned u1 = ((const unsigned*)(y + (size_t)lst[j + 1] * DIM))[lane];
    unsigned u2 = ((const unsigned*)(y + (size_t)lst[j + 2] * DIM))[lane];
    unsigned u3 = ((const unsigned*)(y + (size_t)lst[j + 3] * DIM))[lane];
    a0.x += bf_lo(u0); a0.y += bf_hi(u0);
    a1.x += bf_lo(u1); a1.y += bf_hi(u1);
    a2.x += bf_lo(u2); a2.y += bf_hi(u2);
    a3.x += bf_lo(u3); a3.y += bf_hi(u3);
  }
  for (; j < cnt; ++j) {
    unsigned u0 = ((const unsigned*)(y + (size_t)lst[j] * DIM))[lane];
    a0.x += bf_lo(u0); a0.y += bf_hi(u0);
  }
  float2 r;
  r.x = fmaxf((a0.x + a1.x) + (a2.x + a3.x), 0.f);  // relu
  r.y = fmaxf((a0.y + a1.y) + (a2.y + a3.y), 0.f);

  float s = waveSum(r.x * r.x + r.y * r.y);
  float n = sqrtf(s);
  float nc = fmaxf(n, EPSF);
  float nm = fminf(nc, MAXNORM);
  float scale = 0.5f * logf((1.0f + nm) / (1.0f - nm)) / nc;
  unsigned u = (unsigned)f2bf(r.x * scale) | ((unsigned)f2bf(r.y * scale) << 16);
  ((unsigned*)(tout + (size_t)node * DIM))[lane] = u;
}

// ---------------- layer-2 transform: bf16 tangent in -> (W t + b) -> expmap0 ------
__global__ __launch_bounds__(256, 2) void transform2_mfma(
    const unsigned short* __restrict__ t, const unsigned short* __restrict__ Wb,
    const float* __restrict__ b, unsigned short* __restrict__ y)
{
  const int tid = threadIdx.x;
  const int w = tid >> 6;
  const int l = tid & 63;
  const int lr = l & 15;
  const int lg = l >> 4;

  __shared__ __align__(16) unsigned short At[64 * DIM];

  bf16x8 bf[8][4];
#pragma unroll
  for (int n = 0; n < 8; ++n)
#pragma unroll
    for (int kc = 0; kc < 4; ++kc)
      bf[n][kc] = *(const bf16x8*)(Wb + (n * 16 + lr) * DIM + kc * 32 + lg * 8);

  float bias[8];
#pragma unroll
  for (int n = 0; n < 8; ++n) bias[n] = b[n * 16 + lr];

  const int row = w * 16 + lr;

  for (int tile = blockIdx.x; tile < NTILE; tile += gridDim.x) {
    const int base = tile * 64;
    const int node = base + row;
    __syncthreads();

#pragma unroll
    for (int s = 0; s < 4; ++s) {
      bf16x8 frag;
      if (node < N_NODES)
        frag = *(const bf16x8*)(t + (size_t)node * DIM + lg * 32 + s * 8);
      else
        frag = bf16x8{0, 0, 0, 0, 0, 0, 0, 0};
      int byte = row * 256 + lg * 64 + s * 16;
      byte ^= (row & 7) << 4;
      *(bf16x8*)((char*)At + byte) = frag;
    }
    __syncthreads();

    f32x4 acc[8];
#pragma unroll
    for (int n = 0; n < 8; ++n) {
      acc[n][0] = bias[n]; acc[n][1] = bias[n]; acc[n][2] = bias[n]; acc[n][3] = bias[n];
    }
#pragma unroll
    for (int kc = 0; kc < 4; ++kc) {
      int arow = w * 16 + lr;
      int byte = arow * 256 + kc * 64 + lg * 16;
      byte ^= (arow & 7) << 4;
      bf16x8 af = *(const bf16x8*)((const char*)At + byte);
#pragma unroll
      for (int n = 0; n < 8; ++n)
        acc[n] = __builtin_amdgcn_mfma_f32_16x16x32_bf16(af, bf[n][kc], acc[n], 0, 0, 0);
    }

    float rs[4];
#pragma unroll
    for (int j = 0; j < 4; ++j) {
      float s2 = 0.f;
#pragma unroll
      for (int n = 0; n < 8; ++n) s2 += acc[n][j] * acc[n][j];
      s2 += __shfl_xor(s2, 1, 64);
      s2 += __shfl_xor(s2, 2, 64);
      s2 += __shfl_xor(s2, 4, 64);
      s2 += __shfl_xor(s2, 8, 64);
      float n2 = sqrtf(s2);
      float n2c = fmaxf(n2, EPSF);
      rs[j] = tanhf(n2c) / n2c;
    }
#pragma unroll
    for (int j = 0; j < 4; ++j) {
      int nrow = base + w * 16 + lg * 4 + j;
      if (nrow < N_NODES) {
        unsigned short* yr = y + (size_t)nrow * DIM + lr;
#pragma unroll
        for (int n = 0; n < 8; ++n) yr[n * 16] = f2bf(acc[n][j] * rs[j]);
      }
    }
  }
}

// ---------------- classifier head: out = t2 @ Wc^T + bc via MFMA ----------------
__global__ __launch_bounds__(256) void head_mfma(
    const unsigned short* __restrict__ t2, const float* __restrict__ Wc,
    const float* __restrict__ bc, float* __restrict__ out)
{
  const int base = blockIdx.x * 64;
  const int w = threadIdx.x >> 6;
  const int l = threadIdx.x & 63;
  const int lr = l & 15;
  const int lg = l >> 4;

  bf16x8 bw[4];
#pragma unroll
  for (int kc = 0; kc < 4; ++kc) {
    unsigned short tmp[8];
    if (lr < NCLS) {
      const float* wr = Wc + (size_t)lr * DIM + kc * 32 + lg * 8;
#pragma unroll
      for (int e = 0; e < 8; ++e) tmp[e] = f2bf(wr[e]);
    } else {
#pragma unroll
      for (int e = 0; e < 8; ++e) tmp[e] = 0;
    }
    bw[kc] = *(const bf16x8*)tmp;
  }
  const float bias = (lr < NCLS) ? bc[lr] : 0.f;

  const int arow = base + w * 16 + lr;
  f32x4 acc;
  acc[0] = bias; acc[1] = bias; acc[2] = bias; acc[3] = bias;
#pragma unroll
  for (int kc = 0; kc < 4; ++kc) {
    bf16x8 af;
    if (arow < N_NODES)
      af = *(const bf16x8*)(t2 + (size_t)arow * DIM + kc * 32 + lg * 8);
    else
      af = bf16x8{0, 0, 0, 0, 0, 0, 0, 0};
    acc = __builtin_amdgcn_mfma_f32_16x16x32_bf16(af, bw[kc], acc, 0, 0, 0);
  }

  if (lr < NCLS) {
#pragma unroll
    for (int j = 0; j < 4; ++j) {
      int nrow = base + w * 16 + lg * 4 + j;
      if (nrow < N_NODES) out[(size_t)nrow * NCLS + lr] = acc[j];
    }
  }
}

extern "C" void kernel_launch(void* const* d_in, const int* in_sizes, int n_in,
                              void* d_out, int out_size, void* d_ws, size_t ws_size,
                              hipStream_t stream)
{
  const int* edge = (const int*)d_in[0];
  const int* src = edge;            // edge_index[0]
  const int* dst = edge + N_EDGES;  // edge_index[1]
  const float* x  = (const float*)d_in[1];
  const float* W1 = (const float*)d_in[2];
  const float* b1 = (const float*)d_in[3];
  const float* W2 = (const float*)d_in[4];
  const float* b2 = (const float*)d_in[5];
  const float* Wc = (const float*)d_in[6];
  const float* bc = (const float*)d_in[7];
  float* out = (float*)d_out;

  unsigned short* ybuf = (unsigned short*)d_ws;          // bf16 y [N, D]
  unsigned short* tbuf = ybuf + (size_t)N_NODES * DIM;   // bf16 tangent [N, D]
  unsigned short* W1b = tbuf + (size_t)N_NODES * DIM;
  unsigned short* W2b = W1b + DIM * DIM;
  int* cursor = (int*)(W2b + DIM * DIM);               // 50000 * CURSTRIDE (padded)
  int* ell    = cursor + (size_t)N_NODES * CURSTRIDE;  // 50000 * ELLW

  // --- init (zero padded cursors) + W->bf16 ---
  init_kernel<<<(N_NODES + 255) / 256, 256, 0, stream>>>(cursor, W1, W2, W1b, W2b);

  // --- fused ELL build + layer-1 transform ---
  fill_transform<<<FILL_BLOCKS + XFORM_BLOCKS, 256, 0, stream>>>(
      src, dst, cursor, ell, x, W1b, b1, ybuf);

  // --- gather + relu + logmap -> t (bf16) ---
  gatherT_kernel<<<(N_NODES + 3) / 4, 256, 0, stream>>>(ybuf, cursor, ell, tbuf);

  // --- Layer 2: t (bf16 tangent) -> y2 (bf16) ---
  transform2_mfma<<<512, 256, 0, stream>>>(tbuf, W2b, b2, ybuf);

  // --- gather + relu + logmap -> t2 (bf16) ---
  gatherT_kernel<<<(N_NODES + 3) / 4, 256, 0, stream>>>(ybuf, cursor, ell, tbuf);

  // --- classifier head ---
  head_mfma<<<NTILE, 256, 0, stream>>>(tbuf, Wc, bc, out);
}